// Round 3
// baseline (3738.159 us; speedup 1.0000x reference)
//
#include <hip/hip_runtime.h>
#include <cstddef>

#define N_NODES_  100000
#define N_HEDGES_ 200000
#define E_        1200000
#define G_        512
#define H_        64
#define HE_       35
#define D_        99      // H_+HE_
#define HOUT_     128
#define L_        3

__device__ __forceinline__ float sigm_(float x){ return 1.f/(1.f+__expf(-x)); }
__device__ __forceinline__ float sp_(float x){ return fmaxf(x,0.f)+log1pf(__expf(-fabsf(x))); }

// ---------------- per-call counts ----------------
__global__ void k_counts(const int* __restrict__ ni, const int* __restrict__ hi,
                         int* __restrict__ hcnt, int* __restrict__ ndeg){
  int e = blockIdx.x*256 + threadIdx.x;
  if (e >= E_) return;
  atomicAdd(&hcnt[hi[e]], 1);
  atomicAdd(&ndeg[ni[e]], 1);
}
__global__ void k_gcnt(const int* __restrict__ batch, int* __restrict__ gcnt){
  int n = blockIdx.x*256 + threadIdx.x;
  if (n < N_NODES_) atomicAdd(&gcnt[batch[n]], 1);
}
__global__ void k_inv(const int* __restrict__ hcnt, const int* __restrict__ ndeg,
                      float* __restrict__ hinv, float* __restrict__ ninv){
  int i = blockIdx.x*256 + threadIdx.x;
  if (i < N_HEDGES_) hinv[i] = 1.f/fmaxf((float)hcnt[i], 1.f);
  if (i < N_NODES_)  ninv[i] = 1.f/fmaxf((float)ndeg[i], 1.f);
}

// ---------------- CSR build: scan + fill ----------------
__global__ void k_scan1(const int* __restrict__ cnt, int n, int* __restrict__ off,
                        int* __restrict__ bsum){
  __shared__ int tmp[256];
  int i = blockIdx.x*256 + threadIdx.x;
  int v = (i < n) ? cnt[i] : 0;
  tmp[threadIdx.x] = v;
  __syncthreads();
  for (int d = 1; d < 256; d <<= 1){
    int t = (threadIdx.x >= d) ? tmp[threadIdx.x - d] : 0;
    __syncthreads();
    tmp[threadIdx.x] += t;
    __syncthreads();
  }
  if (i < n) off[i] = tmp[threadIdx.x] - v;       // exclusive within block
  if (threadIdx.x == 255) bsum[blockIdx.x] = tmp[255];
}
__global__ void k_scan2(int* __restrict__ bsum, int nb){   // nb <= 1024, launch 1 block x 1024
  __shared__ int tmp[1024];
  int t = threadIdx.x;
  int v = (t < nb) ? bsum[t] : 0;
  tmp[t] = v;
  __syncthreads();
  for (int d = 1; d < 1024; d <<= 1){
    int x = (t >= d) ? tmp[t - d] : 0;
    __syncthreads();
    tmp[t] += x;
    __syncthreads();
  }
  if (t < nb) bsum[t] = tmp[t] - v;               // exclusive block offsets
}
__global__ void k_scan3(int* __restrict__ off, const int* __restrict__ bsum,
                        int* __restrict__ cur, int n){
  int i = blockIdx.x*256 + threadIdx.x;
  if (i < n){ int v = off[i] + bsum[blockIdx.x]; off[i] = v; cur[i] = v; }
}
__global__ void k_fill(const int* __restrict__ ni, const int* __restrict__ hi,
                       int* __restrict__ ncur, int* __restrict__ hcur,
                       int* __restrict__ edge_n, int* __restrict__ edge_h){
  int e = blockIdx.x*256 + threadIdx.x;
  if (e >= E_) return;
  int n = ni[e], he = hi[e];
  edge_n[atomicAdd(&ncur[n], 1)] = he;   // per-node list of hedge ids
  edge_h[atomicAdd(&hcur[he], 1)] = n;   // per-hedge list of node ids
}

// ---------------- embed: h = x @ We + be  ([100K,92]@[92,64]) ----------------
__global__ void k_embed(const float* __restrict__ x, const float* __restrict__ We,
                        const float* __restrict__ be, float* __restrict__ h){
  __shared__ __align__(16) float As[64*100];
  __shared__ __align__(16) float Ws[64*100];
  int tid = threadIdx.x;
  for (int idx = tid; idx < 64*100; idx += 256){
    int c = idx/100, k = idx - c*100;
    Ws[idx] = (k < 92) ? We[k*64 + c] : 0.f;
  }
  int rt = tid & 15, ct = tid >> 4;
  float bias[4];
  #pragma unroll
  for (int j = 0; j < 4; ++j) bias[j] = be[ct*4 + ((j + ct) & 3)];
  const int ntiles = (N_NODES_ + 63)/64;
  for (int tile = blockIdx.x; tile < ntiles; tile += gridDim.x){
    int rbase = tile*64;
    __syncthreads();
    for (int idx = tid; idx < 64*100; idx += 256){
      int r = idx/100, k = idx - r*100;
      int rg = rbase + r;
      As[idx] = (rg < N_NODES_ && k < 92) ? x[(size_t)rg*92 + k] : 0.f;
    }
    __syncthreads();
    float acc[4][4] = {};
    for (int kc = 0; kc < 25; ++kc){
      float4 av[4], wv[4];
      #pragma unroll
      for (int i = 0; i < 4; ++i) av[i] = *(const float4*)&As[(rt + 16*i)*100 + kc*4];
      #pragma unroll
      for (int j = 0; j < 4; ++j) wv[j] = *(const float4*)&Ws[(ct*4 + ((j + ct) & 3))*100 + kc*4];
      #pragma unroll
      for (int i = 0; i < 4; ++i)
        #pragma unroll
        for (int j = 0; j < 4; ++j)
          acc[i][j] += av[i].x*wv[j].x + av[i].y*wv[j].y + av[i].z*wv[j].z + av[i].w*wv[j].w;
    }
    #pragma unroll
    for (int i = 0; i < 4; ++i){
      int r = rbase + rt + 16*i;
      if (r < N_NODES_){
        #pragma unroll
        for (int j = 0; j < 4; ++j){
          int c = ct*4 + ((j + ct) & 3);
          h[(size_t)r*64 + c] = acc[i][j] + bias[j];
        }
      }
    }
  }
}

// ---------------- fused hedge gather + MLP pre-BN ----------------
// per tile: gather mean node feats via hedge-CSR, then GEMM [64 x 99]@[99 x 70] + stats
__global__ void k_hedge_mlp1(const float* __restrict__ h, const float* __restrict__ hinv,
                             const float* __restrict__ hattr,
                             const int* __restrict__ hedge_off, const int* __restrict__ hcnt,
                             const int* __restrict__ edge_h,
                             const float* __restrict__ Wf1, const float* __restrict__ bf1,
                             const float* __restrict__ Wc1, const float* __restrict__ bc1,
                             float* __restrict__ tfc, float* __restrict__ hstats){
  __shared__ __align__(16) float As[64*100];
  __shared__ __align__(16) float Ws[80*100];
  __shared__ float sstat[160];
  int tid = threadIdx.x;
  for (int idx = tid; idx < 80*100; idx += 256){
    int c = idx/100, k = idx - c*100;
    float w = 0.f;
    if (k < 99){
      if (c < 35)      w = Wf1[k*35 + c];
      else if (c < 70) w = Wc1[k*35 + (c - 35)];
    }
    Ws[idx] = w;
  }
  for (int idx = tid; idx < 160; idx += 256) sstat[idx] = 0.f;
  int lane = tid & 63, wave = tid >> 6;
  int rt = tid & 15, ct = tid >> 4;
  float bias[5];
  #pragma unroll
  for (int j = 0; j < 5; ++j){
    int c = ct*5 + j;
    bias[j] = (c < 35) ? bf1[c] : (c < 70 ? bc1[c - 35] : 0.f);
  }
  for (int tile = blockIdx.x; tile < N_HEDGES_/64; tile += gridDim.x){
    int rbase = tile*64;
    __syncthreads();   // As free (previous GEMM done)
    for (int r = wave; r < 64; r += 4){
      int hh = rbase + r;
      int off = hedge_off[hh], deg = hcnt[hh];
      float acc = 0.f;
      for (int i = 0; i < deg; ++i){
        int n = edge_h[off + i];
        acc += h[(size_t)n*64 + lane];
      }
      As[r*100 + lane] = acc * hinv[hh];
      if (lane < 35)       As[r*100 + 64 + lane] = hattr[(size_t)hh*35 + lane];
      else if (lane == 35) As[r*100 + 99] = 0.f;
    }
    __syncthreads();
    float acc[4][5] = {};
    for (int kc = 0; kc < 25; ++kc){
      float4 av[4], wv[5];
      #pragma unroll
      for (int i = 0; i < 4; ++i) av[i] = *(const float4*)&As[(rt + 16*i)*100 + kc*4];
      #pragma unroll
      for (int j = 0; j < 5; ++j) wv[j] = *(const float4*)&Ws[(ct*5 + j)*100 + kc*4];
      #pragma unroll
      for (int i = 0; i < 4; ++i)
        #pragma unroll
        for (int j = 0; j < 5; ++j)
          acc[i][j] += av[i].x*wv[j].x + av[i].y*wv[j].y + av[i].z*wv[j].z + av[i].w*wv[j].w;
    }
    #pragma unroll
    for (int j = 0; j < 5; ++j){
      int c = ct*5 + j;
      if (c < 70){
        float s = 0.f, q = 0.f;
        #pragma unroll
        for (int i = 0; i < 4; ++i){
          float v = acc[i][j] + bias[j];
          int r = rbase + rt + 16*i;
          tfc[(size_t)r*70 + c] = v;
          s += v; q += v*v;
        }
        atomicAdd(&sstat[c], s);
        atomicAdd(&sstat[80 + c], q);
      }
    }
  }
  __syncthreads();
  for (int idx = tid; idx < 160; idx += 256) atomicAdd(&hstats[idx], sstat[idx]);
}

// ---------------- BN finalize (hedge) ----------------
__global__ void k_bn_fin_hedge(const float* __restrict__ stats,
                               const float* __restrict__ gf, const float* __restrict__ btf,
                               const float* __restrict__ gc, const float* __restrict__ btc,
                               float* __restrict__ ab, float invN){
  int j = threadIdx.x;
  if (j >= 70) return;
  float m = stats[j]*invN;
  float var = stats[80+j]*invN - m*m;
  float gg = (j < 35) ? gf[j] : gc[j-35];
  float bb = (j < 35) ? btf[j] : btc[j-35];
  float a = gg*rsqrtf(var + 1e-5f);
  ab[j] = a; ab[70+j] = bb - m*a;
}

// ---------------- hedge feats + project: heFC = act @ [W2f_bot|W2c_bot] + b2 ----------------
__global__ void k_hedge_feats(const float* __restrict__ tfc, const float* __restrict__ ab,
                              const float* __restrict__ Wf2, const float* __restrict__ bf2,
                              const float* __restrict__ Wc2, const float* __restrict__ bc2,
                              float* __restrict__ heFC){
  __shared__ __align__(16) float As[64*36];
  __shared__ __align__(16) float Ws[128*36];
  int tid = threadIdx.x;
  for (int idx = tid; idx < 128*36; idx += 256){
    int c = idx/36, k = idx - c*36;
    float w = 0.f;
    if (k < 35) w = (c < 64) ? Wf2[(64+k)*64 + c] : Wc2[(64+k)*64 + (c - 64)];
    Ws[idx] = w;
  }
  int rt = tid & 15, ct = tid >> 4;
  float bias[8];
  #pragma unroll
  for (int j = 0; j < 8; ++j){
    int c = ct*8 + ((j + ct) & 7);
    bias[j] = (c < 64) ? bf2[c] : bc2[c - 64];
  }
  for (int tile = blockIdx.x; tile < N_HEDGES_/64; tile += gridDim.x){
    int rbase = tile*64;
    __syncthreads();
    for (int idx = tid; idx < 64*36; idx += 256){
      int r = idx/36, k = idx - r*36;
      float v = 0.f;
      if (k < 35){
        int rg = rbase + r;
        float zf = ab[k]     * tfc[(size_t)rg*70 + k]      + ab[70 + k];
        float zc = ab[35 + k]* tfc[(size_t)rg*70 + 35 + k] + ab[105 + k];
        v = sigm_(zf)*sp_(zc);
      }
      As[idx] = v;
    }
    __syncthreads();
    float acc[4][8] = {};
    for (int kc = 0; kc < 9; ++kc){
      float4 av[4], wv[8];
      #pragma unroll
      for (int i = 0; i < 4; ++i) av[i] = *(const float4*)&As[(rt + 16*i)*36 + kc*4];
      #pragma unroll
      for (int j = 0; j < 8; ++j) wv[j] = *(const float4*)&Ws[(ct*8 + ((j + ct) & 7))*36 + kc*4];
      #pragma unroll
      for (int i = 0; i < 4; ++i)
        #pragma unroll
        for (int j = 0; j < 8; ++j)
          acc[i][j] += av[i].x*wv[j].x + av[i].y*wv[j].y + av[i].z*wv[j].z + av[i].w*wv[j].w;
    }
    #pragma unroll
    for (int i = 0; i < 4; ++i){
      int r = rbase + rt + 16*i;
      #pragma unroll
      for (int j = 0; j < 8; ++j){
        int c = ct*8 + ((j + ct) & 7);
        heFC[(size_t)r*128 + c] = acc[i][j] + bias[j];
      }
    }
  }
}

// ---------------- node projections: nFC = h @ [W2f_top|W2c_top] ----------------
__global__ void k_node_lin(const float* __restrict__ h,
                           const float* __restrict__ Wf2, const float* __restrict__ Wc2,
                           float* __restrict__ nFC){
  __shared__ __align__(16) float As[64*68];
  __shared__ __align__(16) float Ws[128*68];
  int tid = threadIdx.x;
  for (int idx = tid; idx < 128*68; idx += 256){
    int c = idx/68, k = idx - c*68;
    float w = 0.f;
    if (k < 64) w = (c < 64) ? Wf2[k*64 + c] : Wc2[k*64 + (c - 64)];
    Ws[idx] = w;
  }
  int rt = tid & 15, ct = tid >> 4;
  const int ntiles = (N_NODES_ + 63)/64;
  for (int tile = blockIdx.x; tile < ntiles; tile += gridDim.x){
    int rbase = tile*64;
    __syncthreads();
    for (int idx = tid; idx < 64*68; idx += 256){
      int r = idx/68, k = idx - r*68;
      int rg = rbase + r;
      As[idx] = (rg < N_NODES_ && k < 64) ? h[(size_t)rg*64 + k] : 0.f;
    }
    __syncthreads();
    float acc[4][8] = {};
    for (int kc = 0; kc < 17; ++kc){
      float4 av[4], wv[8];
      #pragma unroll
      for (int i = 0; i < 4; ++i) av[i] = *(const float4*)&As[(rt + 16*i)*68 + kc*4];
      #pragma unroll
      for (int j = 0; j < 8; ++j) wv[j] = *(const float4*)&Ws[(ct*8 + ((j + ct) & 7))*68 + kc*4];
      #pragma unroll
      for (int i = 0; i < 4; ++i)
        #pragma unroll
        for (int j = 0; j < 8; ++j)
          acc[i][j] += av[i].x*wv[j].x + av[i].y*wv[j].y + av[i].z*wv[j].z + av[i].w*wv[j].w;
    }
    #pragma unroll
    for (int i = 0; i < 4; ++i){
      int r = rbase + rt + 16*i;
      if (r < N_NODES_){
        #pragma unroll
        for (int j = 0; j < 8; ++j){
          int c = ct*8 + ((j + ct) & 7);
          nFC[(size_t)r*128 + c] = acc[i][j];
        }
      }
    }
  }
}

// ---------------- fused edge: node-CSR gather + gated act + mean + BN stats ----------------
__global__ void k_edge(const float* __restrict__ nFC, const float* __restrict__ heFC,
                       const int* __restrict__ node_off, const int* __restrict__ ndeg,
                       const int* __restrict__ edge_n, const float* __restrict__ ninv,
                       float* __restrict__ nmean, float* __restrict__ nstats){
  int lane = threadIdx.x & 63, wave = threadIdx.x >> 6;
  float s = 0.f, q = 0.f;
  for (int base = blockIdx.x*4; base < N_NODES_; base += gridDim.x*4){
    int n = base + wave;
    if (n < N_NODES_){
      int off = node_off[n], deg = ndeg[n];
      float f0 = nFC[(size_t)n*128 + lane];
      float c0 = nFC[(size_t)n*128 + 64 + lane];
      float acc = 0.f;
      for (int i = 0; i < deg; ++i){
        int he = edge_n[off + i];
        float vF = f0 + heFC[(size_t)he*128 + lane];
        float vC = c0 + heFC[(size_t)he*128 + 64 + lane];
        acc += sigm_(vF)*sp_(vC);
      }
      float m = acc * ninv[n];
      nmean[(size_t)n*64 + lane] = m;
      s += m; q += m*m;
    }
  }
  __shared__ float p1[256], p2[256];
  p1[threadIdx.x] = s; p2[threadIdx.x] = q;
  __syncthreads();
  if (wave == 0){
    float a = p1[lane] + p1[64+lane] + p1[128+lane] + p1[192+lane];
    float b = p2[lane] + p2[64+lane] + p2[128+lane] + p2[192+lane];
    atomicAdd(&nstats[lane], a);
    atomicAdd(&nstats[64+lane], b);
  }
}

__global__ void k_bn_fin_node(const float* __restrict__ stats, const float* __restrict__ g,
                              const float* __restrict__ bt, float* __restrict__ ab, float invN){
  int j = threadIdx.x;
  if (j >= 64) return;
  float m = stats[j]*invN;
  float var = stats[64+j]*invN - m*m;
  float a = g[j]*rsqrtf(var + 1e-5f);
  ab[j] = a; ab[64+j] = bt[j] - m*a;
}

// ---------------- node update: h' = softplus(BN(mean) + h) ----------------
__global__ void k_node_update(const float* __restrict__ nmean, const float* __restrict__ ab,
                              const float* __restrict__ h, float* __restrict__ hout){
  int t = blockIdx.x*256 + threadIdx.x;
  if (t >= N_NODES_*H_) return;
  int f = t & 63;
  float z = ab[f]*nmean[t] + ab[64+f] + h[t];
  hout[t] = sp_(z);
}

// ---------------- graph mean + head ----------------
__global__ void k_graph_agg(const float* __restrict__ h, const int* __restrict__ batch,
                            float* __restrict__ gsum){
  int t = blockIdx.x*256 + threadIdx.x;
  int n = t >> 6; if (n >= N_NODES_) return;
  int f = t & 63;
  atomicAdd(&gsum[(size_t)batch[n]*64+f], h[t]);
}

__global__ void k_head(const float* __restrict__ gsum, const int* __restrict__ gcnt,
                       const float* __restrict__ Wl2, const float* __restrict__ bl2,
                       const float* __restrict__ Wo, const float* __restrict__ bo,
                       float* __restrict__ out){
  __shared__ float gm[64];
  __shared__ float red[128];
  int g = blockIdx.x, j = threadIdx.x;
  if (j < 64) gm[j] = gsum[(size_t)g*64+j] / fmaxf((float)gcnt[g], 1.f);
  __syncthreads();
  float u = bl2[j];
  for (int f = 0; f < 64; ++f) u += gm[f]*Wl2[f*128+j];
  red[j] = sp_(u)*Wo[j];
  __syncthreads();
  for (int s = 64; s > 0; s >>= 1){
    if (j < s) red[j] += red[j+s];
    __syncthreads();
  }
  if (j == 0) out[g] = red[0] + bo[0];
}

extern "C" void kernel_launch(void* const* d_in, const int* in_sizes, int n_in,
                              void* d_out, int out_size, void* d_ws, size_t ws_size,
                              hipStream_t stream){
  (void)in_sizes; (void)n_in; (void)out_size; (void)ws_size;
  const float* x      = (const float*)d_in[0];
  const int*   ni     = (const int*)d_in[1];          // hyperedge_index row 0
  const int*   hi     = ni + E_;                      // row 1
  const float* hattr  = (const float*)d_in[2];
  const int*   batch  = (const int*)d_in[3];
  const float* We     = (const float*)d_in[4];
  const float* be     = (const float*)d_in[5];
  const float* Wf1    = (const float*)d_in[6];
  const float* bf1    = (const float*)d_in[7];
  const float* Wc1    = (const float*)d_in[8];
  const float* bc1    = (const float*)d_in[9];
  const float* Wf2    = (const float*)d_in[10];
  const float* bf2    = (const float*)d_in[11];
  const float* Wc2    = (const float*)d_in[12];
  const float* bc2    = (const float*)d_in[13];
  const float* bn_f_g = (const float*)d_in[14];
  const float* bn_f_b = (const float*)d_in[15];
  const float* bn_c_g = (const float*)d_in[16];
  const float* bn_c_b = (const float*)d_in[17];
  const float* bn_o_g = (const float*)d_in[18];
  const float* bn_o_b = (const float*)d_in[19];
  const float* Wl2    = (const float*)d_in[20];
  const float* bl2    = (const float*)d_in[21];
  const float* Wo     = (const float*)d_in[22];
  const float* bo     = (const float*)d_in[23];

  float* ws = (float*)d_ws;
  size_t o = 0;
  float* h0    = ws + o; o += (size_t)N_NODES_*H_;
  float* h1    = ws + o; o += (size_t)N_NODES_*H_;
  float* tfc   = ws + o; o += (size_t)N_HEDGES_*70;    // 14.0M floats
  float* nFC   = tfc;                                  // alias: tfc consumed before nFC written
  float* heFC  = ws + o; o += (size_t)N_HEDGES_*128;   // 25.6M
  float* nmean = ws + o; o += (size_t)N_NODES_*H_;     // 6.4M
  float* hstats = ws + o; o += 256;
  float* habs   = ws + o; o += 256;
  float* nstats = ws + o; o += 128;
  float* nabs   = ws + o; o += 128;
  float* gsum   = ws + o; o += (size_t)G_*H_;
  float* hinv   = ws + o; o += N_HEDGES_;
  float* ninv   = ws + o; o += N_NODES_;
  int* hcnt     = (int*)(ws + o); o += N_HEDGES_;
  int* ndeg     = (int*)(ws + o); o += N_NODES_;
  int* gcnt     = (int*)(ws + o); o += G_;
  int* node_off = (int*)(ws + o); o += N_NODES_;
  int* hedge_off= (int*)(ws + o); o += N_HEDGES_;
  int* ncur     = (int*)(ws + o); o += N_NODES_;
  int* hcur     = (int*)(ws + o); o += N_HEDGES_;
  int* bsumA    = (int*)(ws + o); o += 1024;
  int* bsumB    = (int*)(ws + o); o += 1024;
  int* edge_n   = (int*)(ws + o); o += E_;
  int* edge_h   = (int*)(ws + o); o += E_;

  hipMemsetAsync(hcnt, 0, sizeof(int)*N_HEDGES_, stream);
  hipMemsetAsync(ndeg, 0, sizeof(int)*N_NODES_, stream);
  hipMemsetAsync(gcnt, 0, sizeof(int)*G_, stream);
  hipMemsetAsync(gsum, 0, sizeof(float)*G_*H_, stream);

  k_counts<<<(E_+255)/256, 256, 0, stream>>>(ni, hi, hcnt, ndeg);
  k_gcnt<<<(N_NODES_+255)/256, 256, 0, stream>>>(batch, gcnt);
  k_inv<<<(N_HEDGES_+255)/256, 256, 0, stream>>>(hcnt, ndeg, hinv, ninv);

  // CSR build (once; reused by all 3 layers)
  k_scan1<<<(N_NODES_+255)/256, 256, 0, stream>>>(ndeg, N_NODES_, node_off, bsumA);
  k_scan2<<<1, 1024, 0, stream>>>(bsumA, (N_NODES_+255)/256);
  k_scan3<<<(N_NODES_+255)/256, 256, 0, stream>>>(node_off, bsumA, ncur, N_NODES_);
  k_scan1<<<(N_HEDGES_+255)/256, 256, 0, stream>>>(hcnt, N_HEDGES_, hedge_off, bsumB);
  k_scan2<<<1, 1024, 0, stream>>>(bsumB, (N_HEDGES_+255)/256);
  k_scan3<<<(N_HEDGES_+255)/256, 256, 0, stream>>>(hedge_off, bsumB, hcur, N_HEDGES_);
  k_fill<<<(E_+255)/256, 256, 0, stream>>>(ni, hi, ncur, hcur, edge_n, edge_h);

  k_embed<<<768, 256, 0, stream>>>(x, We, be, h0);

  float* hcur2 = h0;
  float* hnxt  = h1;
  for (int l = 0; l < L_; ++l){
    const float* Wf1l = Wf1 + (size_t)l*D_*HE_;
    const float* Wc1l = Wc1 + (size_t)l*D_*HE_;
    const float* Wf2l = Wf2 + (size_t)l*D_*H_;
    const float* Wc2l = Wc2 + (size_t)l*D_*H_;

    hipMemsetAsync(hstats, 0, sizeof(float)*160, stream);
    hipMemsetAsync(nstats, 0, sizeof(float)*128, stream);

    k_hedge_mlp1<<<512, 256, 0, stream>>>(hcur2, hinv, hattr, hedge_off, hcnt, edge_h,
                                          Wf1l, bf1 + l*HE_, Wc1l, bc1 + l*HE_, tfc, hstats);
    k_bn_fin_hedge<<<1, 128, 0, stream>>>(hstats, bn_f_g + l*HE_, bn_f_b + l*HE_,
                                          bn_c_g + l*HE_, bn_c_b + l*HE_, habs,
                                          1.f/(float)N_HEDGES_);
    k_hedge_feats<<<1024, 256, 0, stream>>>(tfc, habs, Wf2l, bf2 + l*H_,
                                            Wc2l, bc2 + l*H_, heFC);
    k_node_lin<<<768, 256, 0, stream>>>(hcur2, Wf2l, Wc2l, nFC);
    k_edge<<<2048, 256, 0, stream>>>(nFC, heFC, node_off, ndeg, edge_n, ninv, nmean, nstats);
    k_bn_fin_node<<<1, 64, 0, stream>>>(nstats, bn_o_g + l*H_, bn_o_b + l*H_, nabs,
                                        1.f/(float)N_NODES_);
    k_node_update<<<(N_NODES_*H_+255)/256, 256, 0, stream>>>(nmean, nabs, hcur2, hnxt);
    float* t2 = hcur2; hcur2 = hnxt; hnxt = t2;
  }

  k_graph_agg<<<(N_NODES_*H_+255)/256, 256, 0, stream>>>(hcur2, batch, gsum);
  k_head<<<G_, 128, 0, stream>>>(gsum, gcnt, Wl2, bl2, Wo, bo, (float*)d_out);
}

// Round 4
// 2895.954 us; speedup vs baseline: 1.2908x; 1.2908x over previous
//
#include <hip/hip_runtime.h>
#include <cstddef>

#define N_NODES_  100000
#define N_HEDGES_ 200000
#define E_        1200000
#define G_        512
#define H_        64
#define HE_       35
#define D_        99      // H_+HE_
#define HOUT_     128
#define L_        3

__device__ __forceinline__ float sigm_(float x){ return 1.f/(1.f+__expf(-x)); }
__device__ __forceinline__ float sp_(float x){ return fmaxf(x,0.f)+log1pf(__expf(-fabsf(x))); }

// ---------------- per-call counts ----------------
__global__ void k_counts(const int* __restrict__ ni, const int* __restrict__ hi,
                         int* __restrict__ hcnt, int* __restrict__ ndeg){
  int e = blockIdx.x*256 + threadIdx.x;
  if (e >= E_) return;
  atomicAdd(&hcnt[hi[e]], 1);
  atomicAdd(&ndeg[ni[e]], 1);
}
__global__ void k_gcnt(const int* __restrict__ batch, int* __restrict__ gcnt){
  int n = blockIdx.x*256 + threadIdx.x;
  if (n < N_NODES_) atomicAdd(&gcnt[batch[n]], 1);
}
__global__ void k_inv(const int* __restrict__ hcnt, const int* __restrict__ ndeg,
                      float* __restrict__ hinv, float* __restrict__ ninv){
  int i = blockIdx.x*256 + threadIdx.x;
  if (i < N_HEDGES_) hinv[i] = 1.f/fmaxf((float)hcnt[i], 1.f);
  if (i < N_NODES_)  ninv[i] = 1.f/fmaxf((float)ndeg[i], 1.f);
}

// ---------------- CSR build: scan + fill ----------------
__global__ void k_scan1(const int* __restrict__ cnt, int n, int* __restrict__ off,
                        int* __restrict__ bsum){
  __shared__ int tmp[256];
  int i = blockIdx.x*256 + threadIdx.x;
  int v = (i < n) ? cnt[i] : 0;
  tmp[threadIdx.x] = v;
  __syncthreads();
  for (int d = 1; d < 256; d <<= 1){
    int t = (threadIdx.x >= d) ? tmp[threadIdx.x - d] : 0;
    __syncthreads();
    tmp[threadIdx.x] += t;
    __syncthreads();
  }
  if (i < n) off[i] = tmp[threadIdx.x] - v;       // exclusive within block
  if (threadIdx.x == 255) bsum[blockIdx.x] = tmp[255];
}
__global__ void k_scan2(int* __restrict__ bsum, int nb){   // nb <= 1024
  __shared__ int tmp[1024];
  int t = threadIdx.x;
  int v = (t < nb) ? bsum[t] : 0;
  tmp[t] = v;
  __syncthreads();
  for (int d = 1; d < 1024; d <<= 1){
    int x = (t >= d) ? tmp[t - d] : 0;
    __syncthreads();
    tmp[t] += x;
    __syncthreads();
  }
  if (t < nb) bsum[t] = tmp[t] - v;               // exclusive block offsets
}
__global__ void k_scan3(int* __restrict__ off, const int* __restrict__ bsum,
                        int* __restrict__ cur, int n){
  int i = blockIdx.x*256 + threadIdx.x;
  if (i < n){ int v = off[i] + bsum[blockIdx.x]; off[i] = v; cur[i] = v; }
}
__global__ void k_fill(const int* __restrict__ ni, const int* __restrict__ hi,
                       int* __restrict__ ncur, int* __restrict__ hcur,
                       int* __restrict__ edge_n, int* __restrict__ edge_h){
  int e = blockIdx.x*256 + threadIdx.x;
  if (e >= E_) return;
  int n = ni[e], he = hi[e];
  edge_n[atomicAdd(&ncur[n], 1)] = he;   // per-node list of hedge ids
  edge_h[atomicAdd(&hcur[he], 1)] = n;   // per-hedge list of node ids
}

// ---------------- embed: h = x @ We + be  ([100K,92]@[92,64]) ----------------
__global__ void k_embed(const float* __restrict__ x, const float* __restrict__ We,
                        const float* __restrict__ be, float* __restrict__ h){
  __shared__ __align__(16) float As[64*100];
  __shared__ __align__(16) float Ws[64*100];
  int tid = threadIdx.x;
  for (int idx = tid; idx < 64*100; idx += 256){
    int c = idx/100, k = idx - c*100;
    Ws[idx] = (k < 92) ? We[k*64 + c] : 0.f;
  }
  int rt = tid & 15, ct = tid >> 4;
  float bias[4];
  #pragma unroll
  for (int j = 0; j < 4; ++j) bias[j] = be[ct*4 + ((j + ct) & 3)];
  const int ntiles = (N_NODES_ + 63)/64;
  for (int tile = blockIdx.x; tile < ntiles; tile += gridDim.x){
    int rbase = tile*64;
    __syncthreads();
    for (int idx = tid; idx < 64*100; idx += 256){
      int r = idx/100, k = idx - r*100;
      int rg = rbase + r;
      As[idx] = (rg < N_NODES_ && k < 92) ? x[(size_t)rg*92 + k] : 0.f;
    }
    __syncthreads();
    float acc[4][4] = {};
    for (int kc = 0; kc < 25; ++kc){
      float4 av[4], wv[4];
      #pragma unroll
      for (int i = 0; i < 4; ++i) av[i] = *(const float4*)&As[(rt + 16*i)*100 + kc*4];
      #pragma unroll
      for (int j = 0; j < 4; ++j) wv[j] = *(const float4*)&Ws[(ct*4 + ((j + ct) & 3))*100 + kc*4];
      #pragma unroll
      for (int i = 0; i < 4; ++i)
        #pragma unroll
        for (int j = 0; j < 4; ++j)
          acc[i][j] += av[i].x*wv[j].x + av[i].y*wv[j].y + av[i].z*wv[j].z + av[i].w*wv[j].w;
    }
    #pragma unroll
    for (int i = 0; i < 4; ++i){
      int r = rbase + rt + 16*i;
      if (r < N_NODES_){
        #pragma unroll
        for (int j = 0; j < 4; ++j){
          int c = ct*4 + ((j + ct) & 3);
          h[(size_t)r*64 + c] = acc[i][j] + bias[j];
        }
      }
    }
  }
}

// ---------------- hedge gather: hmean[he] = mean of h rows (CSR, no LDS, max waves) -------
__global__ void __launch_bounds__(256) k_gather_hedge(
    const float* __restrict__ h, const int* __restrict__ hedge_off,
    const int* __restrict__ hcnt, const int* __restrict__ edge_h,
    const float* __restrict__ hinv, float* __restrict__ hmean){
  int w = (blockIdx.x*256 + threadIdx.x) >> 6;
  int lane = threadIdx.x & 63;
  if (w >= N_HEDGES_) return;
  int off = hedge_off[w], deg = hcnt[w];
  float acc = 0.f;
  int i = 0;
  for (; i + 1 < deg; i += 2){
    int n0 = edge_h[off + i], n1 = edge_h[off + i + 1];
    acc += h[(size_t)n0*64 + lane] + h[(size_t)n1*64 + lane];
  }
  if (i < deg) acc += h[(size_t)edge_h[off + i]*64 + lane];
  hmean[(size_t)w*64 + lane] = acc * hinv[w];
}

// ---------------- hedge MLP pre-BN: tfc = [msg@Wf1+bf1 | msg@Wc1+bc1], col stats ----------
// GEMM [200K x 99] @ [99 x 70]; KP=100, Npad=80, NC=5. Streaming, no gather.
__global__ void k_hedge_mlp1(const float* __restrict__ hmean, const float* __restrict__ hattr,
                             const float* __restrict__ Wf1, const float* __restrict__ bf1,
                             const float* __restrict__ Wc1, const float* __restrict__ bc1,
                             float* __restrict__ tfc, float* __restrict__ hstats){
  __shared__ __align__(16) float As[64*100];
  __shared__ __align__(16) float Ws[80*100];
  __shared__ float sstat[160];
  int tid = threadIdx.x;
  for (int idx = tid; idx < 80*100; idx += 256){
    int c = idx/100, k = idx - c*100;
    float w = 0.f;
    if (k < 99){
      if (c < 35)      w = Wf1[k*35 + c];
      else if (c < 70) w = Wc1[k*35 + (c - 35)];
    }
    Ws[idx] = w;
  }
  for (int idx = tid; idx < 160; idx += 256) sstat[idx] = 0.f;
  int rt = tid & 15, ct = tid >> 4;
  float bias[5];
  #pragma unroll
  for (int j = 0; j < 5; ++j){
    int c = ct*5 + j;
    bias[j] = (c < 35) ? bf1[c] : (c < 70 ? bc1[c - 35] : 0.f);
  }
  for (int tile = blockIdx.x; tile < N_HEDGES_/64; tile += gridDim.x){
    int rbase = tile*64;
    __syncthreads();
    for (int idx = tid; idx < 64*100; idx += 256){
      int r = idx/100, k = idx - r*100;
      int rg = rbase + r;
      float v = 0.f;
      if (k < 64)      v = hmean[(size_t)rg*64 + k];
      else if (k < 99) v = hattr[(size_t)rg*35 + (k - 64)];
      As[idx] = v;
    }
    __syncthreads();
    float acc[4][5] = {};
    for (int kc = 0; kc < 25; ++kc){
      float4 av[4], wv[5];
      #pragma unroll
      for (int i = 0; i < 4; ++i) av[i] = *(const float4*)&As[(rt + 16*i)*100 + kc*4];
      #pragma unroll
      for (int j = 0; j < 5; ++j) wv[j] = *(const float4*)&Ws[(ct*5 + j)*100 + kc*4];
      #pragma unroll
      for (int i = 0; i < 4; ++i)
        #pragma unroll
        for (int j = 0; j < 5; ++j)
          acc[i][j] += av[i].x*wv[j].x + av[i].y*wv[j].y + av[i].z*wv[j].z + av[i].w*wv[j].w;
    }
    #pragma unroll
    for (int j = 0; j < 5; ++j){
      int c = ct*5 + j;
      if (c < 70){
        float s = 0.f, q = 0.f;
        #pragma unroll
        for (int i = 0; i < 4; ++i){
          float v = acc[i][j] + bias[j];
          int r = rbase + rt + 16*i;
          tfc[(size_t)r*70 + c] = v;
          s += v; q += v*v;
        }
        atomicAdd(&sstat[c], s);
        atomicAdd(&sstat[80 + c], q);
      }
    }
  }
  __syncthreads();
  for (int idx = tid; idx < 160; idx += 256) atomicAdd(&hstats[idx], sstat[idx]);
}

// ---------------- BN finalize (hedge) ----------------
__global__ void k_bn_fin_hedge(const float* __restrict__ stats,
                               const float* __restrict__ gf, const float* __restrict__ btf,
                               const float* __restrict__ gc, const float* __restrict__ btc,
                               float* __restrict__ ab, float invN){
  int j = threadIdx.x;
  if (j >= 70) return;
  float m = stats[j]*invN;
  float var = stats[80+j]*invN - m*m;
  float gg = (j < 35) ? gf[j] : gc[j-35];
  float bb = (j < 35) ? btf[j] : btc[j-35];
  float a = gg*rsqrtf(var + 1e-5f);
  ab[j] = a; ab[70+j] = bb - m*a;
}

// ---------------- hedge feats + project: heFC = act @ [W2f_bot|W2c_bot] + b2 ----------------
__global__ void k_hedge_feats(const float* __restrict__ tfc, const float* __restrict__ ab,
                              const float* __restrict__ Wf2, const float* __restrict__ bf2,
                              const float* __restrict__ Wc2, const float* __restrict__ bc2,
                              float* __restrict__ heFC){
  __shared__ __align__(16) float As[64*36];
  __shared__ __align__(16) float Ws[128*36];
  int tid = threadIdx.x;
  for (int idx = tid; idx < 128*36; idx += 256){
    int c = idx/36, k = idx - c*36;
    float w = 0.f;
    if (k < 35) w = (c < 64) ? Wf2[(64+k)*64 + c] : Wc2[(64+k)*64 + (c - 64)];
    Ws[idx] = w;
  }
  int rt = tid & 15, ct = tid >> 4;
  float bias[8];
  #pragma unroll
  for (int j = 0; j < 8; ++j){
    int c = ct*8 + ((j + ct) & 7);
    bias[j] = (c < 64) ? bf2[c] : bc2[c - 64];
  }
  for (int tile = blockIdx.x; tile < N_HEDGES_/64; tile += gridDim.x){
    int rbase = tile*64;
    __syncthreads();
    for (int idx = tid; idx < 64*36; idx += 256){
      int r = idx/36, k = idx - r*36;
      float v = 0.f;
      if (k < 35){
        int rg = rbase + r;
        float zf = ab[k]     * tfc[(size_t)rg*70 + k]      + ab[70 + k];
        float zc = ab[35 + k]* tfc[(size_t)rg*70 + 35 + k] + ab[105 + k];
        v = sigm_(zf)*sp_(zc);
      }
      As[idx] = v;
    }
    __syncthreads();
    float acc[4][8] = {};
    for (int kc = 0; kc < 9; ++kc){
      float4 av[4], wv[8];
      #pragma unroll
      for (int i = 0; i < 4; ++i) av[i] = *(const float4*)&As[(rt + 16*i)*36 + kc*4];
      #pragma unroll
      for (int j = 0; j < 8; ++j) wv[j] = *(const float4*)&Ws[(ct*8 + ((j + ct) & 7))*36 + kc*4];
      #pragma unroll
      for (int i = 0; i < 4; ++i)
        #pragma unroll
        for (int j = 0; j < 8; ++j)
          acc[i][j] += av[i].x*wv[j].x + av[i].y*wv[j].y + av[i].z*wv[j].z + av[i].w*wv[j].w;
    }
    #pragma unroll
    for (int i = 0; i < 4; ++i){
      int r = rbase + rt + 16*i;
      #pragma unroll
      for (int j = 0; j < 8; ++j){
        int c = ct*8 + ((j + ct) & 7);
        heFC[(size_t)r*128 + c] = acc[i][j] + bias[j];
      }
    }
  }
}

// ---------------- node projections: nFC = h @ [W2f_top|W2c_top] ----------------
__global__ void k_node_lin(const float* __restrict__ h,
                           const float* __restrict__ Wf2, const float* __restrict__ Wc2,
                           float* __restrict__ nFC){
  __shared__ __align__(16) float As[64*68];
  __shared__ __align__(16) float Ws[128*68];
  int tid = threadIdx.x;
  for (int idx = tid; idx < 128*68; idx += 256){
    int c = idx/68, k = idx - c*68;
    float w = 0.f;
    if (k < 64) w = (c < 64) ? Wf2[k*64 + c] : Wc2[k*64 + (c - 64)];
    Ws[idx] = w;
  }
  int rt = tid & 15, ct = tid >> 4;
  const int ntiles = (N_NODES_ + 63)/64;
  for (int tile = blockIdx.x; tile < ntiles; tile += gridDim.x){
    int rbase = tile*64;
    __syncthreads();
    for (int idx = tid; idx < 64*68; idx += 256){
      int r = idx/68, k = idx - r*68;
      int rg = rbase + r;
      As[idx] = (rg < N_NODES_ && k < 64) ? h[(size_t)rg*64 + k] : 0.f;
    }
    __syncthreads();
    float acc[4][8] = {};
    for (int kc = 0; kc < 17; ++kc){
      float4 av[4], wv[8];
      #pragma unroll
      for (int i = 0; i < 4; ++i) av[i] = *(const float4*)&As[(rt + 16*i)*68 + kc*4];
      #pragma unroll
      for (int j = 0; j < 8; ++j) wv[j] = *(const float4*)&Ws[(ct*8 + ((j + ct) & 7))*68 + kc*4];
      #pragma unroll
      for (int i = 0; i < 4; ++i)
        #pragma unroll
        for (int j = 0; j < 8; ++j)
          acc[i][j] += av[i].x*wv[j].x + av[i].y*wv[j].y + av[i].z*wv[j].z + av[i].w*wv[j].w;
    }
    #pragma unroll
    for (int i = 0; i < 4; ++i){
      int r = rbase + rt + 16*i;
      if (r < N_NODES_){
        #pragma unroll
        for (int j = 0; j < 8; ++j){
          int c = ct*8 + ((j + ct) & 7);
          nFC[(size_t)r*128 + c] = acc[i][j];
        }
      }
    }
  }
}

// ---------------- fused edge: node-CSR gather + gated act + mean + BN stats ----------------
__global__ void k_edge(const float* __restrict__ nFC, const float* __restrict__ heFC,
                       const int* __restrict__ node_off, const int* __restrict__ ndeg,
                       const int* __restrict__ edge_n, const float* __restrict__ ninv,
                       float* __restrict__ nmean, float* __restrict__ nstats){
  int lane = threadIdx.x & 63, wave = threadIdx.x >> 6;
  float s = 0.f, q = 0.f;
  for (int base = blockIdx.x*4; base < N_NODES_; base += gridDim.x*4){
    int n = base + wave;
    if (n < N_NODES_){
      int off = node_off[n], deg = ndeg[n];
      float f0 = nFC[(size_t)n*128 + lane];
      float c0 = nFC[(size_t)n*128 + 64 + lane];
      float acc = 0.f;
      int i = 0;
      for (; i + 1 < deg; i += 2){
        int h0 = edge_n[off + i], h1 = edge_n[off + i + 1];
        float vF0 = f0 + heFC[(size_t)h0*128 + lane];
        float vC0 = c0 + heFC[(size_t)h0*128 + 64 + lane];
        float vF1 = f0 + heFC[(size_t)h1*128 + lane];
        float vC1 = c0 + heFC[(size_t)h1*128 + 64 + lane];
        acc += sigm_(vF0)*sp_(vC0) + sigm_(vF1)*sp_(vC1);
      }
      if (i < deg){
        int he = edge_n[off + i];
        float vF = f0 + heFC[(size_t)he*128 + lane];
        float vC = c0 + heFC[(size_t)he*128 + 64 + lane];
        acc += sigm_(vF)*sp_(vC);
      }
      float m = acc * ninv[n];
      nmean[(size_t)n*64 + lane] = m;
      s += m; q += m*m;
    }
  }
  __shared__ float p1[256], p2[256];
  p1[threadIdx.x] = s; p2[threadIdx.x] = q;
  __syncthreads();
  if (wave == 0){
    float a = p1[lane] + p1[64+lane] + p1[128+lane] + p1[192+lane];
    float b = p2[lane] + p2[64+lane] + p2[128+lane] + p2[192+lane];
    atomicAdd(&nstats[lane], a);
    atomicAdd(&nstats[64+lane], b);
  }
}

__global__ void k_bn_fin_node(const float* __restrict__ stats, const float* __restrict__ g,
                              const float* __restrict__ bt, float* __restrict__ ab, float invN){
  int j = threadIdx.x;
  if (j >= 64) return;
  float m = stats[j]*invN;
  float var = stats[64+j]*invN - m*m;
  float a = g[j]*rsqrtf(var + 1e-5f);
  ab[j] = a; ab[64+j] = bt[j] - m*a;
}

// ---------------- node update: h' = softplus(BN(mean) + h) ----------------
__global__ void k_node_update(const float* __restrict__ nmean, const float* __restrict__ ab,
                              const float* __restrict__ h, float* __restrict__ hout){
  int t = blockIdx.x*256 + threadIdx.x;
  if (t >= N_NODES_*H_) return;
  int f = t & 63;
  float z = ab[f]*nmean[t] + ab[64+f] + h[t];
  hout[t] = sp_(z);
}

// ---------------- graph mean + head ----------------
__global__ void k_graph_agg(const float* __restrict__ h, const int* __restrict__ batch,
                            float* __restrict__ gsum){
  int t = blockIdx.x*256 + threadIdx.x;
  int n = t >> 6; if (n >= N_NODES_) return;
  int f = t & 63;
  atomicAdd(&gsum[(size_t)batch[n]*64+f], h[t]);
}

__global__ void k_head(const float* __restrict__ gsum, const int* __restrict__ gcnt,
                       const float* __restrict__ Wl2, const float* __restrict__ bl2,
                       const float* __restrict__ Wo, const float* __restrict__ bo,
                       float* __restrict__ out){
  __shared__ float gm[64];
  __shared__ float red[128];
  int g = blockIdx.x, j = threadIdx.x;
  if (j < 64) gm[j] = gsum[(size_t)g*64+j] / fmaxf((float)gcnt[g], 1.f);
  __syncthreads();
  float u = bl2[j];
  for (int f = 0; f < 64; ++f) u += gm[f]*Wl2[f*128+j];
  red[j] = sp_(u)*Wo[j];
  __syncthreads();
  for (int s = 64; s > 0; s >>= 1){
    if (j < s) red[j] += red[j+s];
    __syncthreads();
  }
  if (j == 0) out[g] = red[0] + bo[0];
}

extern "C" void kernel_launch(void* const* d_in, const int* in_sizes, int n_in,
                              void* d_out, int out_size, void* d_ws, size_t ws_size,
                              hipStream_t stream){
  (void)in_sizes; (void)n_in; (void)out_size; (void)ws_size;
  const float* x      = (const float*)d_in[0];
  const int*   ni     = (const int*)d_in[1];          // hyperedge_index row 0
  const int*   hi     = ni + E_;                      // row 1
  const float* hattr  = (const float*)d_in[2];
  const int*   batch  = (const int*)d_in[3];
  const float* We     = (const float*)d_in[4];
  const float* be     = (const float*)d_in[5];
  const float* Wf1    = (const float*)d_in[6];
  const float* bf1    = (const float*)d_in[7];
  const float* Wc1    = (const float*)d_in[8];
  const float* bc1    = (const float*)d_in[9];
  const float* Wf2    = (const float*)d_in[10];
  const float* bf2    = (const float*)d_in[11];
  const float* Wc2    = (const float*)d_in[12];
  const float* bc2    = (const float*)d_in[13];
  const float* bn_f_g = (const float*)d_in[14];
  const float* bn_f_b = (const float*)d_in[15];
  const float* bn_c_g = (const float*)d_in[16];
  const float* bn_c_b = (const float*)d_in[17];
  const float* bn_o_g = (const float*)d_in[18];
  const float* bn_o_b = (const float*)d_in[19];
  const float* Wl2    = (const float*)d_in[20];
  const float* bl2    = (const float*)d_in[21];
  const float* Wo     = (const float*)d_in[22];
  const float* bo     = (const float*)d_in[23];

  float* ws = (float*)d_ws;
  size_t o = 0;
  float* h0    = ws + o; o += (size_t)N_NODES_*H_;
  float* h1    = ws + o; o += (size_t)N_NODES_*H_;
  float* tfc   = ws + o; o += (size_t)N_HEDGES_*70;    // 14.0M floats
  float* nFC   = tfc;                                  // alias: tfc consumed before nFC written
  float* heFC  = ws + o; o += (size_t)N_HEDGES_*128;   // 25.6M
  float* hmean = heFC;                                 // alias: hmean dead before heFC written
  float* nmean = ws + o; o += (size_t)N_NODES_*H_;     // 6.4M
  float* hstats = ws + o; o += 256;
  float* habs   = ws + o; o += 256;
  float* nstats = ws + o; o += 128;
  float* nabs   = ws + o; o += 128;
  float* gsum   = ws + o; o += (size_t)G_*H_;
  float* hinv   = ws + o; o += N_HEDGES_;
  float* ninv   = ws + o; o += N_NODES_;
  int* hcnt     = (int*)(ws + o); o += N_HEDGES_;
  int* ndeg     = (int*)(ws + o); o += N_NODES_;
  int* gcnt     = (int*)(ws + o); o += G_;
  int* node_off = (int*)(ws + o); o += N_NODES_;
  int* hedge_off= (int*)(ws + o); o += N_HEDGES_;
  int* ncur     = (int*)(ws + o); o += N_NODES_;
  int* hcur     = (int*)(ws + o); o += N_HEDGES_;
  int* bsumA    = (int*)(ws + o); o += 1024;
  int* bsumB    = (int*)(ws + o); o += 1024;
  int* edge_n   = (int*)(ws + o); o += E_;
  int* edge_h   = (int*)(ws + o); o += E_;

  hipMemsetAsync(hcnt, 0, sizeof(int)*N_HEDGES_, stream);
  hipMemsetAsync(ndeg, 0, sizeof(int)*N_NODES_, stream);
  hipMemsetAsync(gcnt, 0, sizeof(int)*G_, stream);
  hipMemsetAsync(gsum, 0, sizeof(float)*G_*H_, stream);

  k_counts<<<(E_+255)/256, 256, 0, stream>>>(ni, hi, hcnt, ndeg);
  k_gcnt<<<(N_NODES_+255)/256, 256, 0, stream>>>(batch, gcnt);
  k_inv<<<(N_HEDGES_+255)/256, 256, 0, stream>>>(hcnt, ndeg, hinv, ninv);

  // CSR build (once; reused by all 3 layers)
  k_scan1<<<(N_NODES_+255)/256, 256, 0, stream>>>(ndeg, N_NODES_, node_off, bsumA);
  k_scan2<<<1, 1024, 0, stream>>>(bsumA, (N_NODES_+255)/256);
  k_scan3<<<(N_NODES_+255)/256, 256, 0, stream>>>(node_off, bsumA, ncur, N_NODES_);
  k_scan1<<<(N_HEDGES_+255)/256, 256, 0, stream>>>(hcnt, N_HEDGES_, hedge_off, bsumB);
  k_scan2<<<1, 1024, 0, stream>>>(bsumB, (N_HEDGES_+255)/256);
  k_scan3<<<(N_HEDGES_+255)/256, 256, 0, stream>>>(hedge_off, bsumB, hcur, N_HEDGES_);
  k_fill<<<(E_+255)/256, 256, 0, stream>>>(ni, hi, ncur, hcur, edge_n, edge_h);

  k_embed<<<768, 256, 0, stream>>>(x, We, be, h0);

  float* hcur2 = h0;
  float* hnxt  = h1;
  for (int l = 0; l < L_; ++l){
    const float* Wf1l = Wf1 + (size_t)l*D_*HE_;
    const float* Wc1l = Wc1 + (size_t)l*D_*HE_;
    const float* Wf2l = Wf2 + (size_t)l*D_*H_;
    const float* Wc2l = Wc2 + (size_t)l*D_*H_;

    hipMemsetAsync(hstats, 0, sizeof(float)*160, stream);
    hipMemsetAsync(nstats, 0, sizeof(float)*128, stream);

    k_gather_hedge<<<(N_HEDGES_*64)/256, 256, 0, stream>>>(hcur2, hedge_off, hcnt, edge_h,
                                                           hinv, hmean);
    k_hedge_mlp1<<<512, 256, 0, stream>>>(hmean, hattr, Wf1l, bf1 + l*HE_,
                                          Wc1l, bc1 + l*HE_, tfc, hstats);
    k_bn_fin_hedge<<<1, 128, 0, stream>>>(hstats, bn_f_g + l*HE_, bn_f_b + l*HE_,
                                          bn_c_g + l*HE_, bn_c_b + l*HE_, habs,
                                          1.f/(float)N_HEDGES_);
    k_hedge_feats<<<1024, 256, 0, stream>>>(tfc, habs, Wf2l, bf2 + l*H_,
                                            Wc2l, bc2 + l*H_, heFC);
    k_node_lin<<<768, 256, 0, stream>>>(hcur2, Wf2l, Wc2l, nFC);
    k_edge<<<2048, 256, 0, stream>>>(nFC, heFC, node_off, ndeg, edge_n, ninv, nmean, nstats);
    k_bn_fin_node<<<1, 64, 0, stream>>>(nstats, bn_o_g + l*H_, bn_o_b + l*H_, nabs,
                                        1.f/(float)N_NODES_);
    k_node_update<<<(N_NODES_*H_+255)/256, 256, 0, stream>>>(nmean, nabs, hcur2, hnxt);
    float* t2 = hcur2; hcur2 = hnxt; hnxt = t2;
  }

  k_graph_agg<<<(N_NODES_*H_+255)/256, 256, 0, stream>>>(hcur2, batch, gsum);
  k_head<<<G_, 128, 0, stream>>>(gsum, gcnt, Wl2, bl2, Wo, bo, (float*)d_out);
}

// Round 6
// 1951.319 us; speedup vs baseline: 1.9157x; 1.4841x over previous
//
#include <hip/hip_runtime.h>
#include <cstddef>

#define N_NODES_  100000
#define N_HEDGES_ 200000
#define E_        1200000
#define G_        512
#define H_        64
#define HE_       35
#define D_        99      // H_+HE_
#define HOUT_     128
#define L_        3

typedef __fp16 h2_t __attribute__((ext_vector_type(2)));

__device__ __forceinline__ float sigm_(float x){
  return __builtin_amdgcn_rcpf(1.f + __expf(-x));
}
__device__ __forceinline__ float sp_(float x){
  return fmaxf(x, 0.f) + __logf(1.f + __expf(-fabsf(x)));
}
__device__ __forceinline__ float gate_(float F, float C){ return sigm_(F)*sp_(C); }

// ---------------- per-call counts ----------------
__global__ void k_counts(const int* __restrict__ ni, const int* __restrict__ hi,
                         int* __restrict__ hcnt, int* __restrict__ ndeg){
  int e = blockIdx.x*256 + threadIdx.x;
  if (e >= E_) return;
  atomicAdd(&hcnt[hi[e]], 1);
  atomicAdd(&ndeg[ni[e]], 1);
}
__global__ void k_gcnt(const int* __restrict__ batch, int* __restrict__ gcnt){
  int n = blockIdx.x*256 + threadIdx.x;
  if (n < N_NODES_) atomicAdd(&gcnt[batch[n]], 1);
}
__global__ void k_inv(const int* __restrict__ hcnt, const int* __restrict__ ndeg,
                      float* __restrict__ hinv, float* __restrict__ ninv){
  int i = blockIdx.x*256 + threadIdx.x;
  if (i < N_HEDGES_) hinv[i] = 1.f/fmaxf((float)hcnt[i], 1.f);
  if (i < N_NODES_)  ninv[i] = 1.f/fmaxf((float)ndeg[i], 1.f);
}

// ---------------- CSR build: scan + fill ----------------
__global__ void k_scan1(const int* __restrict__ cnt, int n, int* __restrict__ off,
                        int* __restrict__ bsum){
  __shared__ int tmp[256];
  int i = blockIdx.x*256 + threadIdx.x;
  int v = (i < n) ? cnt[i] : 0;
  tmp[threadIdx.x] = v;
  __syncthreads();
  for (int d = 1; d < 256; d <<= 1){
    int t = (threadIdx.x >= d) ? tmp[threadIdx.x - d] : 0;
    __syncthreads();
    tmp[threadIdx.x] += t;
    __syncthreads();
  }
  if (i < n) off[i] = tmp[threadIdx.x] - v;
  if (threadIdx.x == 255) bsum[blockIdx.x] = tmp[255];
}
__global__ void k_scan2(int* __restrict__ bsum, int nb){
  __shared__ int tmp[1024];
  int t = threadIdx.x;
  int v = (t < nb) ? bsum[t] : 0;
  tmp[t] = v;
  __syncthreads();
  for (int d = 1; d < 1024; d <<= 1){
    int x = (t >= d) ? tmp[t - d] : 0;
    __syncthreads();
    tmp[t] += x;
    __syncthreads();
  }
  if (t < nb) bsum[t] = tmp[t] - v;
}
__global__ void k_scan3(int* __restrict__ off, const int* __restrict__ bsum,
                        int* __restrict__ cur, int n){
  int i = blockIdx.x*256 + threadIdx.x;
  if (i < n){ int v = off[i] + bsum[blockIdx.x]; off[i] = v; cur[i] = v; }
}
__global__ void k_fill(const int* __restrict__ ni, const int* __restrict__ hi,
                       int* __restrict__ ncur, int* __restrict__ hcur,
                       int* __restrict__ edge_n, int* __restrict__ edge_h){
  int e = blockIdx.x*256 + threadIdx.x;
  if (e >= E_) return;
  int n = ni[e], he = hi[e];
  edge_n[atomicAdd(&ncur[n], 1)] = he;
  edge_h[atomicAdd(&hcur[he], 1)] = n;
}

// ---------------- embed: h = x @ We + be ----------------
__global__ void k_embed(const float* __restrict__ x, const float* __restrict__ We,
                        const float* __restrict__ be, float* __restrict__ h){
  __shared__ __align__(16) float As[64*100];
  __shared__ __align__(16) float Ws[64*100];
  int tid = threadIdx.x;
  for (int idx = tid; idx < 64*100; idx += 256){
    int c = idx/100, k = idx - c*100;
    Ws[idx] = (k < 92) ? We[k*64 + c] : 0.f;
  }
  int rt = tid & 15, ct = tid >> 4;
  float bias[4];
  #pragma unroll
  for (int j = 0; j < 4; ++j) bias[j] = be[ct*4 + ((j + ct) & 3)];
  const int ntiles = (N_NODES_ + 63)/64;
  for (int tile = blockIdx.x; tile < ntiles; tile += gridDim.x){
    int rbase = tile*64;
    __syncthreads();
    for (int idx = tid; idx < 64*100; idx += 256){
      int r = idx/100, k = idx - r*100;
      int rg = rbase + r;
      As[idx] = (rg < N_NODES_ && k < 92) ? x[(size_t)rg*92 + k] : 0.f;
    }
    __syncthreads();
    float acc[4][4] = {};
    for (int kc = 0; kc < 25; ++kc){
      float4 av[4], wv[4];
      #pragma unroll
      for (int i = 0; i < 4; ++i) av[i] = *(const float4*)&As[(rt + 16*i)*100 + kc*4];
      #pragma unroll
      for (int j = 0; j < 4; ++j) wv[j] = *(const float4*)&Ws[(ct*4 + ((j + ct) & 3))*100 + kc*4];
      #pragma unroll
      for (int i = 0; i < 4; ++i)
        #pragma unroll
        for (int j = 0; j < 4; ++j)
          acc[i][j] += av[i].x*wv[j].x + av[i].y*wv[j].y + av[i].z*wv[j].z + av[i].w*wv[j].w;
    }
    #pragma unroll
    for (int i = 0; i < 4; ++i){
      int r = rbase + rt + 16*i;
      if (r < N_NODES_){
        #pragma unroll
        for (int j = 0; j < 4; ++j){
          int c = ct*4 + ((j + ct) & 3);
          h[(size_t)r*64 + c] = acc[i][j] + bias[j];
        }
      }
    }
  }
}

// ---------------- hedge gather: hmean[he] = mean of h rows ----------------
__global__ void __launch_bounds__(256) k_gather_hedge(
    const float* __restrict__ h, const int* __restrict__ hedge_off,
    const int* __restrict__ hcnt, const int* __restrict__ edge_h,
    const float* __restrict__ hinv, float* __restrict__ hmean){
  int w = (blockIdx.x*256 + threadIdx.x) >> 6;
  int lane = threadIdx.x & 63;
  if (w >= N_HEDGES_) return;
  int off = __builtin_amdgcn_readfirstlane(hedge_off[w]);
  int deg = __builtin_amdgcn_readfirstlane(hcnt[w]);
  float acc = 0.f;
  int i = 0;
  for (; i + 3 < deg; i += 4){
    int n0 = edge_h[off+i], n1 = edge_h[off+i+1], n2 = edge_h[off+i+2], n3 = edge_h[off+i+3];
    acc += h[(size_t)n0*64 + lane] + h[(size_t)n1*64 + lane]
         + h[(size_t)n2*64 + lane] + h[(size_t)n3*64 + lane];
  }
  for (; i < deg; ++i) acc += h[(size_t)edge_h[off + i]*64 + lane];
  hmean[(size_t)w*64 + lane] = acc * hinv[w];
}

// ---------------- hedge MLP pre-BN: tfc = [msg@Wf1+bf1 | msg@Wc1+bc1], col stats ----------
__global__ void k_hedge_mlp1(const float* __restrict__ hmean, const float* __restrict__ hattr,
                             const float* __restrict__ Wf1, const float* __restrict__ bf1,
                             const float* __restrict__ Wc1, const float* __restrict__ bc1,
                             float* __restrict__ tfc, float* __restrict__ hstats){
  __shared__ __align__(16) float As[64*100];
  __shared__ __align__(16) float Ws[80*100];
  __shared__ float sstat[160];
  int tid = threadIdx.x;
  for (int idx = tid; idx < 80*100; idx += 256){
    int c = idx/100, k = idx - c*100;
    float w = 0.f;
    if (k < 99){
      if (c < 35)      w = Wf1[k*35 + c];
      else if (c < 70) w = Wc1[k*35 + (c - 35)];
    }
    Ws[idx] = w;
  }
  for (int idx = tid; idx < 160; idx += 256) sstat[idx] = 0.f;
  int rt = tid & 15, ct = tid >> 4;
  float bias[5];
  #pragma unroll
  for (int j = 0; j < 5; ++j){
    int c = ct*5 + j;
    bias[j] = (c < 35) ? bf1[c] : (c < 70 ? bc1[c - 35] : 0.f);
  }
  for (int tile = blockIdx.x; tile < N_HEDGES_/64; tile += gridDim.x){
    int rbase = tile*64;
    __syncthreads();
    for (int idx = tid; idx < 64*100; idx += 256){
      int r = idx/100, k = idx - r*100;
      int rg = rbase + r;
      float v = 0.f;
      if (k < 64)      v = hmean[(size_t)rg*64 + k];
      else if (k < 99) v = hattr[(size_t)rg*35 + (k - 64)];
      As[idx] = v;
    }
    __syncthreads();
    float acc[4][5] = {};
    for (int kc = 0; kc < 25; ++kc){
      float4 av[4], wv[5];
      #pragma unroll
      for (int i = 0; i < 4; ++i) av[i] = *(const float4*)&As[(rt + 16*i)*100 + kc*4];
      #pragma unroll
      for (int j = 0; j < 5; ++j) wv[j] = *(const float4*)&Ws[(ct*5 + j)*100 + kc*4];
      #pragma unroll
      for (int i = 0; i < 4; ++i)
        #pragma unroll
        for (int j = 0; j < 5; ++j)
          acc[i][j] += av[i].x*wv[j].x + av[i].y*wv[j].y + av[i].z*wv[j].z + av[i].w*wv[j].w;
    }
    #pragma unroll
    for (int j = 0; j < 5; ++j){
      int c = ct*5 + j;
      if (c < 70){
        float s = 0.f, q = 0.f;
        #pragma unroll
        for (int i = 0; i < 4; ++i){
          float v = acc[i][j] + bias[j];
          int r = rbase + rt + 16*i;
          tfc[(size_t)r*70 + c] = v;
          s += v; q += v*v;
        }
        atomicAdd(&sstat[c], s);
        atomicAdd(&sstat[80 + c], q);
      }
    }
  }
  __syncthreads();
  for (int idx = tid; idx < 160; idx += 256) atomicAdd(&hstats[idx], sstat[idx]);
}

// ---------------- BN finalize (hedge) ----------------
__global__ void k_bn_fin_hedge(const float* __restrict__ stats,
                               const float* __restrict__ gf, const float* __restrict__ btf,
                               const float* __restrict__ gc, const float* __restrict__ btc,
                               float* __restrict__ ab, float invN){
  int j = threadIdx.x;
  if (j >= 70) return;
  float m = stats[j]*invN;
  float var = stats[80+j]*invN - m*m;
  float gg = (j < 35) ? gf[j] : gc[j-35];
  float bb = (j < 35) ? btf[j] : btc[j-35];
  float a = gg*rsqrtf(var + 1e-5f);
  ab[j] = a; ab[70+j] = bb - m*a;
}

// ---------------- hedge feats + project, packed fp16 out ----------------
__global__ void k_hedge_feats(const float* __restrict__ tfc, const float* __restrict__ ab,
                              const float* __restrict__ Wf2, const float* __restrict__ bf2,
                              const float* __restrict__ Wc2, const float* __restrict__ bc2,
                              h2_t* __restrict__ heFC2){
  __shared__ __align__(16) float As[64*36];
  __shared__ __align__(16) float Ws[128*36];   // rows 0-63: Wf2_bot col, 64-127: Wc2_bot col
  int tid = threadIdx.x;
  for (int idx = tid; idx < 128*36; idx += 256){
    int c = idx/36, k = idx - c*36;
    float w = 0.f;
    if (k < 35) w = (c < 64) ? Wf2[(64+k)*64 + c] : Wc2[(64+k)*64 + (c - 64)];
    Ws[idx] = w;
  }
  int rt = tid & 15, ct = tid >> 4;
  float biasF[4], biasC[4];
  #pragma unroll
  for (int j = 0; j < 4; ++j){ biasF[j] = bf2[ct*4 + j]; biasC[j] = bc2[ct*4 + j]; }
  for (int tile = blockIdx.x; tile < N_HEDGES_/64; tile += gridDim.x){
    int rbase = tile*64;
    __syncthreads();
    for (int idx = tid; idx < 64*36; idx += 256){
      int r = idx/36, k = idx - r*36;
      float v = 0.f;
      if (k < 35){
        int rg = rbase + r;
        float zf = ab[k]     * tfc[(size_t)rg*70 + k]      + ab[70 + k];
        float zc = ab[35 + k]* tfc[(size_t)rg*70 + 35 + k] + ab[105 + k];
        v = sigm_(zf)*sp_(zc);
      }
      As[idx] = v;
    }
    __syncthreads();
    float accF[4][4] = {}, accC[4][4] = {};
    for (int kc = 0; kc < 9; ++kc){
      float4 av[4], wF[4], wC[4];
      #pragma unroll
      for (int i = 0; i < 4; ++i) av[i] = *(const float4*)&As[(rt + 16*i)*36 + kc*4];
      #pragma unroll
      for (int j = 0; j < 4; ++j){
        wF[j] = *(const float4*)&Ws[(ct*4 + j)*36 + kc*4];
        wC[j] = *(const float4*)&Ws[(64 + ct*4 + j)*36 + kc*4];
      }
      #pragma unroll
      for (int i = 0; i < 4; ++i)
        #pragma unroll
        for (int j = 0; j < 4; ++j){
          accF[i][j] += av[i].x*wF[j].x + av[i].y*wF[j].y + av[i].z*wF[j].z + av[i].w*wF[j].w;
          accC[i][j] += av[i].x*wC[j].x + av[i].y*wC[j].y + av[i].z*wC[j].z + av[i].w*wC[j].w;
        }
    }
    #pragma unroll
    for (int i = 0; i < 4; ++i){
      int r = rbase + rt + 16*i;
      #pragma unroll
      for (int j = 0; j < 4; ++j){
        heFC2[(size_t)r*64 + ct*4 + j] =
            __builtin_amdgcn_cvt_pkrtz(accF[i][j] + biasF[j], accC[i][j] + biasC[j]);
      }
    }
  }
}

// ---------------- node projections, packed fp16 out ----------------
__global__ void k_node_lin(const float* __restrict__ h,
                           const float* __restrict__ Wf2, const float* __restrict__ Wc2,
                           h2_t* __restrict__ nFC2){
  __shared__ __align__(16) float As[64*68];
  __shared__ __align__(16) float Ws[128*68];
  int tid = threadIdx.x;
  for (int idx = tid; idx < 128*68; idx += 256){
    int c = idx/68, k = idx - c*68;
    float w = 0.f;
    if (k < 64) w = (c < 64) ? Wf2[k*64 + c] : Wc2[k*64 + (c - 64)];
    Ws[idx] = w;
  }
  int rt = tid & 15, ct = tid >> 4;
  const int ntiles = (N_NODES_ + 63)/64;
  for (int tile = blockIdx.x; tile < ntiles; tile += gridDim.x){
    int rbase = tile*64;
    __syncthreads();
    for (int idx = tid; idx < 64*68; idx += 256){
      int r = idx/68, k = idx - r*68;
      int rg = rbase + r;
      As[idx] = (rg < N_NODES_ && k < 64) ? h[(size_t)rg*64 + k] : 0.f;
    }
    __syncthreads();
    float accF[4][4] = {}, accC[4][4] = {};
    for (int kc = 0; kc < 17; ++kc){
      float4 av[4], wF[4], wC[4];
      #pragma unroll
      for (int i = 0; i < 4; ++i) av[i] = *(const float4*)&As[(rt + 16*i)*68 + kc*4];
      #pragma unroll
      for (int j = 0; j < 4; ++j){
        wF[j] = *(const float4*)&Ws[(ct*4 + j)*68 + kc*4];
        wC[j] = *(const float4*)&Ws[(64 + ct*4 + j)*68 + kc*4];
      }
      #pragma unroll
      for (int i = 0; i < 4; ++i)
        #pragma unroll
        for (int j = 0; j < 4; ++j){
          accF[i][j] += av[i].x*wF[j].x + av[i].y*wF[j].y + av[i].z*wF[j].z + av[i].w*wF[j].w;
          accC[i][j] += av[i].x*wC[j].x + av[i].y*wC[j].y + av[i].z*wC[j].z + av[i].w*wC[j].w;
        }
    }
    #pragma unroll
    for (int i = 0; i < 4; ++i){
      int r = rbase + rt + 16*i;
      if (r < N_NODES_){
        #pragma unroll
        for (int j = 0; j < 4; ++j){
          nFC2[(size_t)r*64 + ct*4 + j] =
              __builtin_amdgcn_cvt_pkrtz(accF[i][j], accC[i][j]);
        }
      }
    }
  }
}

// ---------------- fused edge: node-CSR gather (fp16 packed) + gated act + mean + stats ------
__global__ void k_edge(const h2_t* __restrict__ nFC2, const h2_t* __restrict__ heFC2,
                       const int* __restrict__ node_off, const int* __restrict__ ndeg,
                       const int* __restrict__ edge_n, const float* __restrict__ ninv,
                       float* __restrict__ nmean, float* __restrict__ nstats){
  int lane = threadIdx.x & 63, wave = threadIdx.x >> 6;
  float s = 0.f, q = 0.f;
  for (int base = blockIdx.x*4; base < N_NODES_; base += gridDim.x*4){
    int n = base + wave;
    if (n < N_NODES_){
      int off = __builtin_amdgcn_readfirstlane(node_off[n]);
      int deg = __builtin_amdgcn_readfirstlane(ndeg[n]);
      h2_t p0 = nFC2[(size_t)n*64 + lane];
      float f0 = (float)p0.x, c0 = (float)p0.y;
      float acc = 0.f;
      int i = 0;
      for (; i + 3 < deg; i += 4){
        int e0 = edge_n[off+i], e1 = edge_n[off+i+1], e2 = edge_n[off+i+2], e3 = edge_n[off+i+3];
        h2_t a0 = heFC2[(size_t)e0*64 + lane];
        h2_t a1 = heFC2[(size_t)e1*64 + lane];
        h2_t a2 = heFC2[(size_t)e2*64 + lane];
        h2_t a3 = heFC2[(size_t)e3*64 + lane];
        acc += gate_(f0 + (float)a0.x, c0 + (float)a0.y)
             + gate_(f0 + (float)a1.x, c0 + (float)a1.y)
             + gate_(f0 + (float)a2.x, c0 + (float)a2.y)
             + gate_(f0 + (float)a3.x, c0 + (float)a3.y);
      }
      for (; i < deg; ++i){
        h2_t a = heFC2[(size_t)edge_n[off+i]*64 + lane];
        acc += gate_(f0 + (float)a.x, c0 + (float)a.y);
      }
      float m = acc * ninv[n];
      nmean[(size_t)n*64 + lane] = m;
      s += m; q += m*m;
    }
  }
  __shared__ float p1[256], p2[256];
  p1[threadIdx.x] = s; p2[threadIdx.x] = q;
  __syncthreads();
  if (wave == 0){
    float a = p1[lane] + p1[64+lane] + p1[128+lane] + p1[192+lane];
    float b = p2[lane] + p2[64+lane] + p2[128+lane] + p2[192+lane];
    atomicAdd(&nstats[lane], a);
    atomicAdd(&nstats[64+lane], b);
  }
}

__global__ void k_bn_fin_node(const float* __restrict__ stats, const float* __restrict__ g,
                              const float* __restrict__ bt, float* __restrict__ ab, float invN){
  int j = threadIdx.x;
  if (j >= 64) return;
  float m = stats[j]*invN;
  float var = stats[64+j]*invN - m*m;
  float a = g[j]*rsqrtf(var + 1e-5f);
  ab[j] = a; ab[64+j] = bt[j] - m*a;
}

// ---------------- node update: h' = softplus(BN(mean) + h) ----------------
__global__ void k_node_update(const float* __restrict__ nmean, const float* __restrict__ ab,
                              const float* __restrict__ h, float* __restrict__ hout){
  int t = blockIdx.x*256 + threadIdx.x;
  if (t >= N_NODES_*H_) return;
  int f = t & 63;
  float z = ab[f]*nmean[t] + ab[64+f] + h[t];
  hout[t] = sp_(z);
}

// ---------------- graph mean + head ----------------
__global__ void k_graph_agg(const float* __restrict__ h, const int* __restrict__ batch,
                            float* __restrict__ gsum){
  int t = blockIdx.x*256 + threadIdx.x;
  int n = t >> 6; if (n >= N_NODES_) return;
  int f = t & 63;
  atomicAdd(&gsum[(size_t)batch[n]*64+f], h[t]);
}

__global__ void k_head(const float* __restrict__ gsum, const int* __restrict__ gcnt,
                       const float* __restrict__ Wl2, const float* __restrict__ bl2,
                       const float* __restrict__ Wo, const float* __restrict__ bo,
                       float* __restrict__ out){
  __shared__ float gm[64];
  __shared__ float red[128];
  int g = blockIdx.x, j = threadIdx.x;
  if (j < 64) gm[j] = gsum[(size_t)g*64+j] / fmaxf((float)gcnt[g], 1.f);
  __syncthreads();
  float u = bl2[j];
  for (int f = 0; f < 64; ++f) u += gm[f]*Wl2[f*128+j];
  red[j] = sp_(u)*Wo[j];
  __syncthreads();
  for (int s = 64; s > 0; s >>= 1){
    if (j < s) red[j] += red[j+s];
    __syncthreads();
  }
  if (j == 0) out[g] = red[0] + bo[0];
}

extern "C" void kernel_launch(void* const* d_in, const int* in_sizes, int n_in,
                              void* d_out, int out_size, void* d_ws, size_t ws_size,
                              hipStream_t stream){
  (void)in_sizes; (void)n_in; (void)out_size; (void)ws_size;
  const float* x      = (const float*)d_in[0];
  const int*   ni     = (const int*)d_in[1];
  const int*   hi     = ni + E_;
  const float* hattr  = (const float*)d_in[2];
  const int*   batch  = (const int*)d_in[3];
  const float* We     = (const float*)d_in[4];
  const float* be     = (const float*)d_in[5];
  const float* Wf1    = (const float*)d_in[6];
  const float* bf1    = (const float*)d_in[7];
  const float* Wc1    = (const float*)d_in[8];
  const float* bc1    = (const float*)d_in[9];
  const float* Wf2    = (const float*)d_in[10];
  const float* bf2    = (const float*)d_in[11];
  const float* Wc2    = (const float*)d_in[12];
  const float* bc2    = (const float*)d_in[13];
  const float* bn_f_g = (const float*)d_in[14];
  const float* bn_f_b = (const float*)d_in[15];
  const float* bn_c_g = (const float*)d_in[16];
  const float* bn_c_b = (const float*)d_in[17];
  const float* bn_o_g = (const float*)d_in[18];
  const float* bn_o_b = (const float*)d_in[19];
  const float* Wl2    = (const float*)d_in[20];
  const float* bl2    = (const float*)d_in[21];
  const float* Wo     = (const float*)d_in[22];
  const float* bo     = (const float*)d_in[23];

  float* ws = (float*)d_ws;
  size_t o = 0;
  float* h0    = ws + o; o += (size_t)N_NODES_*H_;
  float* h1    = ws + o; o += (size_t)N_NODES_*H_;
  float* tfc   = ws + o; o += (size_t)N_HEDGES_*70;    // 14.0M floats
  h2_t*  nFC2  = (h2_t*)tfc;                            // alias: tfc consumed before nFC2 written
  float* hmean = ws + o; o += (size_t)N_HEDGES_*H_;    // 12.8M floats
  h2_t*  heFC2 = (h2_t*)hmean;                          // alias: hmean dead before heFC2 written
  float* nmean = ws + o; o += (size_t)N_NODES_*H_;
  float* hstats = ws + o; o += 256;
  float* habs   = ws + o; o += 256;
  float* nstats = ws + o; o += 128;
  float* nabs   = ws + o; o += 128;
  float* gsum   = ws + o; o += (size_t)G_*H_;
  float* hinv   = ws + o; o += N_HEDGES_;
  float* ninv   = ws + o; o += N_NODES_;
  int* hcnt     = (int*)(ws + o); o += N_HEDGES_;
  int* ndeg     = (int*)(ws + o); o += N_NODES_;
  int* gcnt     = (int*)(ws + o); o += G_;
  int* node_off = (int*)(ws + o); o += N_NODES_;
  int* hedge_off= (int*)(ws + o); o += N_HEDGES_;
  int* ncur     = (int*)(ws + o); o += N_NODES_;
  int* hcur     = (int*)(ws + o); o += N_HEDGES_;
  int* bsumA    = (int*)(ws + o); o += 1024;
  int* bsumB    = (int*)(ws + o); o += 1024;
  int* edge_n   = (int*)(ws + o); o += E_;
  int* edge_h   = (int*)(ws + o); o += E_;

  hipMemsetAsync(hcnt, 0, sizeof(int)*N_HEDGES_, stream);
  hipMemsetAsync(ndeg, 0, sizeof(int)*N_NODES_, stream);
  hipMemsetAsync(gcnt, 0, sizeof(int)*G_, stream);
  hipMemsetAsync(gsum, 0, sizeof(float)*G_*H_, stream);

  k_counts<<<(E_+255)/256, 256, 0, stream>>>(ni, hi, hcnt, ndeg);
  k_gcnt<<<(N_NODES_+255)/256, 256, 0, stream>>>(batch, gcnt);
  k_inv<<<(N_HEDGES_+255)/256, 256, 0, stream>>>(hcnt, ndeg, hinv, ninv);

  k_scan1<<<(N_NODES_+255)/256, 256, 0, stream>>>(ndeg, N_NODES_, node_off, bsumA);
  k_scan2<<<1, 1024, 0, stream>>>(bsumA, (N_NODES_+255)/256);
  k_scan3<<<(N_NODES_+255)/256, 256, 0, stream>>>(node_off, bsumA, ncur, N_NODES_);
  k_scan1<<<(N_HEDGES_+255)/256, 256, 0, stream>>>(hcnt, N_HEDGES_, hedge_off, bsumB);
  k_scan2<<<1, 1024, 0, stream>>>(bsumB, (N_HEDGES_+255)/256);
  k_scan3<<<(N_HEDGES_+255)/256, 256, 0, stream>>>(hedge_off, bsumB, hcur, N_HEDGES_);
  k_fill<<<(E_+255)/256, 256, 0, stream>>>(ni, hi, ncur, hcur, edge_n, edge_h);

  k_embed<<<768, 256, 0, stream>>>(x, We, be, h0);

  float* hcur2 = h0;
  float* hnxt  = h1;
  for (int l = 0; l < L_; ++l){
    const float* Wf1l = Wf1 + (size_t)l*D_*HE_;
    const float* Wc1l = Wc1 + (size_t)l*D_*HE_;
    const float* Wf2l = Wf2 + (size_t)l*D_*H_;
    const float* Wc2l = Wc2 + (size_t)l*D_*H_;

    hipMemsetAsync(hstats, 0, sizeof(float)*160, stream);
    hipMemsetAsync(nstats, 0, sizeof(float)*128, stream);

    k_gather_hedge<<<(N_HEDGES_*64)/256, 256, 0, stream>>>(hcur2, hedge_off, hcnt, edge_h,
                                                           hinv, hmean);
    k_hedge_mlp1<<<512, 256, 0, stream>>>(hmean, hattr, Wf1l, bf1 + l*HE_,
                                          Wc1l, bc1 + l*HE_, tfc, hstats);
    k_bn_fin_hedge<<<1, 128, 0, stream>>>(hstats, bn_f_g + l*HE_, bn_f_b + l*HE_,
                                          bn_c_g + l*HE_, bn_c_b + l*HE_, habs,
                                          1.f/(float)N_HEDGES_);
    k_hedge_feats<<<1024, 256, 0, stream>>>(tfc, habs, Wf2l, bf2 + l*H_,
                                            Wc2l, bc2 + l*H_, heFC2);
    k_node_lin<<<768, 256, 0, stream>>>(hcur2, Wf2l, Wc2l, nFC2);
    k_edge<<<2048, 256, 0, stream>>>(nFC2, heFC2, node_off, ndeg, edge_n, ninv, nmean, nstats);
    k_bn_fin_node<<<1, 64, 0, stream>>>(nstats, bn_o_g + l*H_, bn_o_b + l*H_, nabs,
                                        1.f/(float)N_NODES_);
    k_node_update<<<(N_NODES_*H_+255)/256, 256, 0, stream>>>(nmean, nabs, hcur2, hnxt);
    float* t2 = hcur2; hcur2 = hnxt; hnxt = t2;
  }

  k_graph_agg<<<(N_NODES_*H_+255)/256, 256, 0, stream>>>(hcur2, batch, gsum);
  k_head<<<G_, 128, 0, stream>>>(gsum, gcnt, Wl2, bl2, Wo, bo, (float*)d_out);
}

// Round 7
// 1610.397 us; speedup vs baseline: 2.3213x; 1.2117x over previous
//
#include <hip/hip_runtime.h>
#include <cstddef>

#define N_NODES_  100000
#define N_HEDGES_ 200000
#define E_        1200000
#define G_        512
#define H_        64
#define HE_       35
#define D_        99      // H_+HE_
#define HOUT_     128
#define L_        3

typedef unsigned int u32;
typedef _Float16 f2_t __attribute__((ext_vector_type(2)));

__device__ __forceinline__ float sigm_(float x){
  return __builtin_amdgcn_rcpf(1.f + __expf(-x));
}
__device__ __forceinline__ float sp_(float x){
  return fmaxf(x, 0.f) + __logf(1.f + __expf(-fabsf(x)));
}
__device__ __forceinline__ float gate_(float F, float C){ return sigm_(F)*sp_(C); }

__device__ __forceinline__ u32 pk_(float a, float b){
  return __builtin_bit_cast(u32, __builtin_amdgcn_cvt_pkrtz(a, b));
}
__device__ __forceinline__ float dot2_(u32 a, u32 b, float c){
#if __has_builtin(__builtin_amdgcn_fdot2)
  return __builtin_amdgcn_fdot2(__builtin_bit_cast(f2_t, a),
                                __builtin_bit_cast(f2_t, b), c, false);
#else
  f2_t x = __builtin_bit_cast(f2_t, a), y = __builtin_bit_cast(f2_t, b);
  return c + (float)x[0]*(float)y[0] + (float)x[1]*(float)y[1];
#endif
}
__device__ __forceinline__ float lo_(u32 a){ return (float)__builtin_bit_cast(f2_t, a)[0]; }
__device__ __forceinline__ float hi_(u32 a){ return (float)__builtin_bit_cast(f2_t, a)[1]; }

// ---------------- per-call counts ----------------
__global__ void k_counts(const int* __restrict__ ni, const int* __restrict__ hi,
                         int* __restrict__ hcnt, int* __restrict__ ndeg){
  int e = blockIdx.x*256 + threadIdx.x;
  if (e >= E_) return;
  atomicAdd(&hcnt[hi[e]], 1);
  atomicAdd(&ndeg[ni[e]], 1);
}
__global__ void k_gcnt(const int* __restrict__ batch, int* __restrict__ gcnt){
  int n = blockIdx.x*256 + threadIdx.x;
  if (n < N_NODES_) atomicAdd(&gcnt[batch[n]], 1);
}
__global__ void k_inv(const int* __restrict__ hcnt, const int* __restrict__ ndeg,
                      float* __restrict__ hinv, float* __restrict__ ninv){
  int i = blockIdx.x*256 + threadIdx.x;
  if (i < N_HEDGES_) hinv[i] = 1.f/fmaxf((float)hcnt[i], 1.f);
  if (i < N_NODES_)  ninv[i] = 1.f/fmaxf((float)ndeg[i], 1.f);
}

// ---------------- CSR build: scan + fill ----------------
__global__ void k_scan1(const int* __restrict__ cnt, int n, int* __restrict__ off,
                        int* __restrict__ bsum){
  __shared__ int tmp[256];
  int i = blockIdx.x*256 + threadIdx.x;
  int v = (i < n) ? cnt[i] : 0;
  tmp[threadIdx.x] = v;
  __syncthreads();
  for (int d = 1; d < 256; d <<= 1){
    int t = (threadIdx.x >= d) ? tmp[threadIdx.x - d] : 0;
    __syncthreads();
    tmp[threadIdx.x] += t;
    __syncthreads();
  }
  if (i < n) off[i] = tmp[threadIdx.x] - v;
  if (threadIdx.x == 255) bsum[blockIdx.x] = tmp[255];
}
__global__ void k_scan2(int* __restrict__ bsum, int nb){
  __shared__ int tmp[1024];
  int t = threadIdx.x;
  int v = (t < nb) ? bsum[t] : 0;
  tmp[t] = v;
  __syncthreads();
  for (int d = 1; d < 1024; d <<= 1){
    int x = (t >= d) ? tmp[t - d] : 0;
    __syncthreads();
    tmp[t] += x;
    __syncthreads();
  }
  if (t < nb) bsum[t] = tmp[t] - v;
}
__global__ void k_scan3(int* __restrict__ off, const int* __restrict__ bsum,
                        int* __restrict__ cur, int n){
  int i = blockIdx.x*256 + threadIdx.x;
  if (i < n){ int v = off[i] + bsum[blockIdx.x]; off[i] = v; cur[i] = v; }
}
__global__ void k_fill(const int* __restrict__ ni, const int* __restrict__ hi,
                       int* __restrict__ ncur, int* __restrict__ hcur,
                       int* __restrict__ edge_n, int* __restrict__ edge_h){
  int e = blockIdx.x*256 + threadIdx.x;
  if (e >= E_) return;
  int n = ni[e], he = hi[e];
  edge_n[atomicAdd(&ncur[n], 1)] = he;
  edge_h[atomicAdd(&hcur[he], 1)] = n;
}

// ---------------- pack hattr to fp16 pairs [NH][18] ----------------
__global__ void k_hattr_pack(const float* __restrict__ hattr, u32* __restrict__ hattr16){
  int i = blockIdx.x*256 + threadIdx.x;
  if (i >= N_HEDGES_*18) return;
  int he = i/18, p = i - he*18;
  int k0 = 2*p, k1 = 2*p + 1;
  float w0 = (k0 < 35) ? hattr[(size_t)he*35 + k0] : 0.f;
  float w1 = (k1 < 35) ? hattr[(size_t)he*35 + k1] : 0.f;
  hattr16[i] = pk_(w0, w1);
}

// ---------------- embed: h = x @ We + be ; also packed fp16 mirror ----------------
__global__ void k_embed(const float* __restrict__ x, const float* __restrict__ We,
                        const float* __restrict__ be, float* __restrict__ h,
                        u32* __restrict__ h16){
  __shared__ __align__(16) float As[64*100];
  __shared__ __align__(16) float Ws[64*100];
  int tid = threadIdx.x;
  for (int idx = tid; idx < 64*100; idx += 256){
    int c = idx/100, k = idx - c*100;
    Ws[idx] = (k < 92) ? We[k*64 + c] : 0.f;
  }
  int rt = tid & 15, ct = tid >> 4;
  float bias[4];
  #pragma unroll
  for (int j = 0; j < 4; ++j) bias[j] = be[ct*4 + j];
  const int ntiles = (N_NODES_ + 63)/64;
  for (int tile = blockIdx.x; tile < ntiles; tile += gridDim.x){
    int rbase = tile*64;
    __syncthreads();
    for (int idx = tid; idx < 64*100; idx += 256){
      int r = idx/100, k = idx - r*100;
      int rg = rbase + r;
      As[idx] = (rg < N_NODES_ && k < 92) ? x[(size_t)rg*92 + k] : 0.f;
    }
    __syncthreads();
    float acc[4][4] = {};
    for (int kc = 0; kc < 25; ++kc){
      float4 av[4], wv[4];
      #pragma unroll
      for (int i = 0; i < 4; ++i) av[i] = *(const float4*)&As[(rt + 16*i)*100 + kc*4];
      #pragma unroll
      for (int j = 0; j < 4; ++j) wv[j] = *(const float4*)&Ws[(ct*4 + j)*100 + kc*4];
      #pragma unroll
      for (int i = 0; i < 4; ++i)
        #pragma unroll
        for (int j = 0; j < 4; ++j)
          acc[i][j] += av[i].x*wv[j].x + av[i].y*wv[j].y + av[i].z*wv[j].z + av[i].w*wv[j].w;
    }
    #pragma unroll
    for (int i = 0; i < 4; ++i){
      int r = rbase + rt + 16*i;
      if (r < N_NODES_){
        float4 st;
        st.x = acc[i][0] + bias[0]; st.y = acc[i][1] + bias[1];
        st.z = acc[i][2] + bias[2]; st.w = acc[i][3] + bias[3];
        *(float4*)&h[(size_t)r*64 + ct*4] = st;
        h16[(size_t)r*32 + ct*2]     = pk_(st.x, st.y);
        h16[(size_t)r*32 + ct*2 + 1] = pk_(st.z, st.w);
      }
    }
  }
}

// ---------------- hedge gather (fp16): hmean16[he] = mean of h16 rows ----------------
__global__ void __launch_bounds__(256) k_gather_hedge(
    const u32* __restrict__ h16, const int* __restrict__ hedge_off,
    const int* __restrict__ hcnt, const int* __restrict__ edge_h,
    const float* __restrict__ hinv, u32* __restrict__ hmean16){
  int w = (blockIdx.x*256 + threadIdx.x) >> 5;
  int p = threadIdx.x & 31;
  if (w >= N_HEDGES_) return;
  int off = hedge_off[w], deg = hcnt[w];
  float ax = 0.f, ay = 0.f;
  int i = 0;
  for (; i + 3 < deg; i += 4){
    int n0 = edge_h[off+i], n1 = edge_h[off+i+1], n2 = edge_h[off+i+2], n3 = edge_h[off+i+3];
    u32 u0 = h16[(size_t)n0*32 + p], u1 = h16[(size_t)n1*32 + p];
    u32 u2 = h16[(size_t)n2*32 + p], u3 = h16[(size_t)n3*32 + p];
    ax += lo_(u0) + lo_(u1) + lo_(u2) + lo_(u3);
    ay += hi_(u0) + hi_(u1) + hi_(u2) + hi_(u3);
  }
  for (; i < deg; ++i){
    u32 u = h16[(size_t)edge_h[off+i]*32 + p];
    ax += lo_(u); ay += hi_(u);
  }
  float inv = hinv[w];
  hmean16[(size_t)w*32 + p] = pk_(ax*inv, ay*inv);
}

// ---------------- hedge MLP pre-BN (dot2): tfc = [msg@Wf1|msg@Wc1]+b, col stats ----------
// K = 100 elems (64 h + 36 hattr_pad) = 50 pairs, padded to 52; 13 chunks of 4 words.
__global__ void k_hedge_mlp1(const u32* __restrict__ hmean16, const u32* __restrict__ hattr16,
                             const float* __restrict__ Wf1, const float* __restrict__ bf1,
                             const float* __restrict__ Wc1, const float* __restrict__ bc1,
                             float* __restrict__ tfc, float* __restrict__ hstats){
  __shared__ __align__(16) u32 As16[64*52];
  __shared__ __align__(16) u32 Ws16[80*52];
  __shared__ float sstat[160];
  int tid = threadIdx.x;
  for (int idx = tid; idx < 80*52; idx += 256){
    int c = idx/52, kk = idx - c*52;
    int k0 = 2*kk, k1 = 2*kk + 1;
    float w0 = 0.f, w1 = 0.f;
    if (c < 70){
      if (k0 < 99) w0 = (c < 35) ? Wf1[k0*35 + c] : Wc1[k0*35 + (c-35)];
      if (k1 < 99) w1 = (c < 35) ? Wf1[k1*35 + c] : Wc1[k1*35 + (c-35)];
    }
    Ws16[idx] = pk_(w0, w1);
  }
  for (int idx = tid; idx < 160; idx += 256) sstat[idx] = 0.f;
  int rt = tid & 15, ct = tid >> 4;
  float bias[5];
  #pragma unroll
  for (int j = 0; j < 5; ++j){
    int c = ct*5 + j;
    bias[j] = (c < 35) ? bf1[c] : (c < 70 ? bc1[c - 35] : 0.f);
  }
  for (int tile = blockIdx.x; tile < N_HEDGES_/64; tile += gridDim.x){
    int rbase = tile*64;
    __syncthreads();
    for (int idx = tid; idx < 64*52; idx += 256){
      int r = idx/52, kk = idx - r*52;
      int rg = rbase + r;
      u32 v = 0;
      if (kk < 32)      v = hmean16[(size_t)rg*32 + kk];
      else if (kk < 50) v = hattr16[(size_t)rg*18 + (kk - 32)];
      As16[idx] = v;
    }
    __syncthreads();
    float acc[4][5] = {};
    for (int kc = 0; kc < 13; ++kc){
      uint4 av[4], wv[5];
      #pragma unroll
      for (int i = 0; i < 4; ++i) av[i] = *(const uint4*)&As16[(rt + 16*i)*52 + kc*4];
      #pragma unroll
      for (int j = 0; j < 5; ++j) wv[j] = *(const uint4*)&Ws16[(ct*5 + j)*52 + kc*4];
      #pragma unroll
      for (int i = 0; i < 4; ++i)
        #pragma unroll
        for (int j = 0; j < 5; ++j){
          float a = acc[i][j];
          a = dot2_(av[i].x, wv[j].x, a);
          a = dot2_(av[i].y, wv[j].y, a);
          a = dot2_(av[i].z, wv[j].z, a);
          a = dot2_(av[i].w, wv[j].w, a);
          acc[i][j] = a;
        }
    }
    #pragma unroll
    for (int j = 0; j < 5; ++j){
      int c = ct*5 + j;
      if (c < 70){
        float s = 0.f, q = 0.f;
        #pragma unroll
        for (int i = 0; i < 4; ++i){
          float v = acc[i][j] + bias[j];
          int r = rbase + rt + 16*i;
          tfc[(size_t)r*70 + c] = v;
          s += v; q += v*v;
        }
        atomicAdd(&sstat[c], s);
        atomicAdd(&sstat[80 + c], q);
      }
    }
  }
  __syncthreads();
  for (int idx = tid; idx < 160; idx += 256) atomicAdd(&hstats[idx], sstat[idx]);
}

// ---------------- BN finalize (hedge) ----------------
__global__ void k_bn_fin_hedge(const float* __restrict__ stats,
                               const float* __restrict__ gf, const float* __restrict__ btf,
                               const float* __restrict__ gc, const float* __restrict__ btc,
                               float* __restrict__ ab, float invN){
  int j = threadIdx.x;
  if (j >= 70) return;
  float m = stats[j]*invN;
  float var = stats[80+j]*invN - m*m;
  float gg = (j < 35) ? gf[j] : gc[j-35];
  float bb = (j < 35) ? btf[j] : btc[j-35];
  float a = gg*rsqrtf(var + 1e-5f);
  ab[j] = a; ab[70+j] = bb - m*a;
}

// ---------------- hedge feats + project (dot2, K=35 pad 40): heFC2 packed fp16 ------------
__global__ void k_hedge_feats(const float* __restrict__ tfc, const float* __restrict__ ab,
                              const float* __restrict__ Wf2, const float* __restrict__ bf2,
                              const float* __restrict__ Wc2, const float* __restrict__ bc2,
                              u32* __restrict__ heFC2){
  __shared__ __align__(16) u32 As16[64*20];
  __shared__ __align__(16) u32 Ws16[128*20];
  int tid = threadIdx.x;
  for (int idx = tid; idx < 128*20; idx += 256){
    int c = idx/20, kk = idx - c*20;
    int k0 = 2*kk, k1 = 2*kk + 1;
    float w0 = 0.f, w1 = 0.f;
    if (k0 < 35) w0 = (c < 64) ? Wf2[(64+k0)*64 + c] : Wc2[(64+k0)*64 + (c-64)];
    if (k1 < 35) w1 = (c < 64) ? Wf2[(64+k1)*64 + c] : Wc2[(64+k1)*64 + (c-64)];
    Ws16[idx] = pk_(w0, w1);
  }
  int rt = tid & 15, ct = tid >> 4;
  float biasF[4], biasC[4];
  #pragma unroll
  for (int j = 0; j < 4; ++j){ biasF[j] = bf2[ct*4 + j]; biasC[j] = bc2[ct*4 + j]; }
  for (int tile = blockIdx.x; tile < N_HEDGES_/64; tile += gridDim.x){
    int rbase = tile*64;
    __syncthreads();
    for (int idx = tid; idx < 64*20; idx += 256){
      int r = idx/20, kk = idx - r*20;
      int rg = rbase + r;
      int k0 = 2*kk, k1 = 2*kk + 1;
      float a0 = 0.f, a1 = 0.f;
      if (k0 < 35){
        float zf = ab[k0]    * tfc[(size_t)rg*70 + k0]      + ab[70 + k0];
        float zc = ab[35+k0] * tfc[(size_t)rg*70 + 35 + k0] + ab[105 + k0];
        a0 = gate_(zf, zc);
      }
      if (k1 < 35){
        float zf = ab[k1]    * tfc[(size_t)rg*70 + k1]      + ab[70 + k1];
        float zc = ab[35+k1] * tfc[(size_t)rg*70 + 35 + k1] + ab[105 + k1];
        a1 = gate_(zf, zc);
      }
      As16[idx] = pk_(a0, a1);
    }
    __syncthreads();
    float accF[4][4] = {}, accC[4][4] = {};
    for (int kc = 0; kc < 5; ++kc){
      uint4 av[4], wF[4], wC[4];
      #pragma unroll
      for (int i = 0; i < 4; ++i) av[i] = *(const uint4*)&As16[(rt + 16*i)*20 + kc*4];
      #pragma unroll
      for (int j = 0; j < 4; ++j){
        wF[j] = *(const uint4*)&Ws16[(ct*4 + j)*20 + kc*4];
        wC[j] = *(const uint4*)&Ws16[(64 + ct*4 + j)*20 + kc*4];
      }
      #pragma unroll
      for (int i = 0; i < 4; ++i)
        #pragma unroll
        for (int j = 0; j < 4; ++j){
          float f = accF[i][j], c = accC[i][j];
          f = dot2_(av[i].x, wF[j].x, f); c = dot2_(av[i].x, wC[j].x, c);
          f = dot2_(av[i].y, wF[j].y, f); c = dot2_(av[i].y, wC[j].y, c);
          f = dot2_(av[i].z, wF[j].z, f); c = dot2_(av[i].z, wC[j].z, c);
          f = dot2_(av[i].w, wF[j].w, f); c = dot2_(av[i].w, wC[j].w, c);
          accF[i][j] = f; accC[i][j] = c;
        }
    }
    #pragma unroll
    for (int i = 0; i < 4; ++i){
      int r = rbase + rt + 16*i;
      #pragma unroll
      for (int j = 0; j < 4; ++j){
        heFC2[(size_t)r*64 + ct*4 + j] = pk_(accF[i][j] + biasF[j], accC[i][j] + biasC[j]);
      }
    }
  }
}

// ---------------- node projections (dot2, K=64): nFC2 packed fp16 ----------------
// A-tile stride padded to 36 words (avoid 16-way bank conflict at stride 32).
__global__ void k_node_lin(const u32* __restrict__ h16,
                           const float* __restrict__ Wf2, const float* __restrict__ Wc2,
                           u32* __restrict__ nFC2){
  __shared__ __align__(16) u32 As16[64*36];
  __shared__ __align__(16) u32 Ws16[128*36];
  int tid = threadIdx.x;
  for (int idx = tid; idx < 128*36; idx += 256){
    int c = idx/36, kk = idx - c*36;
    int k0 = 2*kk, k1 = 2*kk + 1;
    float w0 = 0.f, w1 = 0.f;
    if (k0 < 64) w0 = (c < 64) ? Wf2[k0*64 + c] : Wc2[k0*64 + (c-64)];
    if (k1 < 64) w1 = (c < 64) ? Wf2[k1*64 + c] : Wc2[k1*64 + (c-64)];
    Ws16[idx] = pk_(w0, w1);
  }
  int rt = tid & 15, ct = tid >> 4;
  const int ntiles = (N_NODES_ + 63)/64;
  for (int tile = blockIdx.x; tile < ntiles; tile += gridDim.x){
    int rbase = tile*64;
    __syncthreads();
    for (int idx = tid; idx < 64*36; idx += 256){
      int r = idx/36, kk = idx - r*36;
      int rg = rbase + r;
      As16[idx] = (rg < N_NODES_ && kk < 32) ? h16[(size_t)rg*32 + kk] : 0u;
    }
    __syncthreads();
    float accF[4][4] = {}, accC[4][4] = {};
    for (int kc = 0; kc < 8; ++kc){
      uint4 av[4], wF[4], wC[4];
      #pragma unroll
      for (int i = 0; i < 4; ++i) av[i] = *(const uint4*)&As16[(rt + 16*i)*36 + kc*4];
      #pragma unroll
      for (int j = 0; j < 4; ++j){
        wF[j] = *(const uint4*)&Ws16[(ct*4 + j)*36 + kc*4];
        wC[j] = *(const uint4*)&Ws16[(64 + ct*4 + j)*36 + kc*4];
      }
      #pragma unroll
      for (int i = 0; i < 4; ++i)
        #pragma unroll
        for (int j = 0; j < 4; ++j){
          float f = accF[i][j], c = accC[i][j];
          f = dot2_(av[i].x, wF[j].x, f); c = dot2_(av[i].x, wC[j].x, c);
          f = dot2_(av[i].y, wF[j].y, f); c = dot2_(av[i].y, wC[j].y, c);
          f = dot2_(av[i].z, wF[j].z, f); c = dot2_(av[i].z, wC[j].z, c);
          f = dot2_(av[i].w, wF[j].w, f); c = dot2_(av[i].w, wC[j].w, c);
          accF[i][j] = f; accC[i][j] = c;
        }
    }
    #pragma unroll
    for (int i = 0; i < 4; ++i){
      int r = rbase + rt + 16*i;
      if (r < N_NODES_){
        #pragma unroll
        for (int j = 0; j < 4; ++j){
          nFC2[(size_t)r*64 + ct*4 + j] = pk_(accF[i][j], accC[i][j]);
        }
      }
    }
  }
}

// ---------------- fused edge: node-CSR gather (fp16 packed) + gated act + mean + stats ------
__global__ void k_edge(const u32* __restrict__ nFC2, const u32* __restrict__ heFC2,
                       const int* __restrict__ node_off, const int* __restrict__ ndeg,
                       const int* __restrict__ edge_n, const float* __restrict__ ninv,
                       float* __restrict__ nmean, float* __restrict__ nstats){
  int lane = threadIdx.x & 63, wave = threadIdx.x >> 6;
  float s = 0.f, q = 0.f;
  for (int base = blockIdx.x*4; base < N_NODES_; base += gridDim.x*4){
    int n = base + wave;
    if (n < N_NODES_){
      int off = __builtin_amdgcn_readfirstlane(node_off[n]);
      int deg = __builtin_amdgcn_readfirstlane(ndeg[n]);
      u32 p0 = nFC2[(size_t)n*64 + lane];
      float f0 = lo_(p0), c0 = hi_(p0);
      float acc = 0.f;
      int i = 0;
      for (; i + 3 < deg; i += 4){
        int e0 = edge_n[off+i], e1 = edge_n[off+i+1], e2 = edge_n[off+i+2], e3 = edge_n[off+i+3];
        u32 a0 = heFC2[(size_t)e0*64 + lane];
        u32 a1 = heFC2[(size_t)e1*64 + lane];
        u32 a2 = heFC2[(size_t)e2*64 + lane];
        u32 a3 = heFC2[(size_t)e3*64 + lane];
        acc += gate_(f0 + lo_(a0), c0 + hi_(a0))
             + gate_(f0 + lo_(a1), c0 + hi_(a1))
             + gate_(f0 + lo_(a2), c0 + hi_(a2))
             + gate_(f0 + lo_(a3), c0 + hi_(a3));
      }
      for (; i < deg; ++i){
        u32 a = heFC2[(size_t)edge_n[off+i]*64 + lane];
        acc += gate_(f0 + lo_(a), c0 + hi_(a));
      }
      float m = acc * ninv[n];
      nmean[(size_t)n*64 + lane] = m;
      s += m; q += m*m;
    }
  }
  __shared__ float p1[256], p2[256];
  p1[threadIdx.x] = s; p2[threadIdx.x] = q;
  __syncthreads();
  if (wave == 0){
    float a = p1[lane] + p1[64+lane] + p1[128+lane] + p1[192+lane];
    float b = p2[lane] + p2[64+lane] + p2[128+lane] + p2[192+lane];
    atomicAdd(&nstats[lane], a);
    atomicAdd(&nstats[64+lane], b);
  }
}

__global__ void k_bn_fin_node(const float* __restrict__ stats, const float* __restrict__ g,
                              const float* __restrict__ bt, float* __restrict__ ab, float invN){
  int j = threadIdx.x;
  if (j >= 64) return;
  float m = stats[j]*invN;
  float var = stats[64+j]*invN - m*m;
  float a = g[j]*rsqrtf(var + 1e-5f);
  ab[j] = a; ab[64+j] = bt[j] - m*a;
}

// ---------------- node update: h' = softplus(BN(mean) + h), + fp16 mirror ----------------
__global__ void k_node_update(const float* __restrict__ nmean, const float* __restrict__ ab,
                              const float* __restrict__ h, float* __restrict__ hout,
                              u32* __restrict__ h16out){
  int t = blockIdx.x*256 + threadIdx.x;
  if (t >= N_NODES_*32) return;
  int p = t & 31;
  int f0 = 2*p, f1 = 2*p + 1;
  float2 nm = ((const float2*)nmean)[t];
  float2 hh = ((const float2*)h)[t];
  float r0 = sp_(ab[f0]*nm.x + ab[64+f0] + hh.x);
  float r1 = sp_(ab[f1]*nm.y + ab[64+f1] + hh.y);
  float2 st; st.x = r0; st.y = r1;
  ((float2*)hout)[t] = st;
  h16out[t] = pk_(r0, r1);
}

// ---------------- graph mean + head ----------------
__global__ void k_graph_agg(const float* __restrict__ h, const int* __restrict__ batch,
                            float* __restrict__ gsum){
  int t = blockIdx.x*256 + threadIdx.x;
  int n = t >> 6; if (n >= N_NODES_) return;
  int f = t & 63;
  atomicAdd(&gsum[(size_t)batch[n]*64+f], h[t]);
}

__global__ void k_head(const float* __restrict__ gsum, const int* __restrict__ gcnt,
                       const float* __restrict__ Wl2, const float* __restrict__ bl2,
                       const float* __restrict__ Wo, const float* __restrict__ bo,
                       float* __restrict__ out){
  __shared__ float gm[64];
  __shared__ float red[128];
  int g = blockIdx.x, j = threadIdx.x;
  if (j < 64) gm[j] = gsum[(size_t)g*64+j] / fmaxf((float)gcnt[g], 1.f);
  __syncthreads();
  float u = bl2[j];
  for (int f = 0; f < 64; ++f) u += gm[f]*Wl2[f*128+j];
  red[j] = sp_(u)*Wo[j];
  __syncthreads();
  for (int s = 64; s > 0; s >>= 1){
    if (j < s) red[j] += red[j+s];
    __syncthreads();
  }
  if (j == 0) out[g] = red[0] + bo[0];
}

extern "C" void kernel_launch(void* const* d_in, const int* in_sizes, int n_in,
                              void* d_out, int out_size, void* d_ws, size_t ws_size,
                              hipStream_t stream){
  (void)in_sizes; (void)n_in; (void)out_size; (void)ws_size;
  const float* x      = (const float*)d_in[0];
  const int*   ni     = (const int*)d_in[1];
  const int*   hi     = ni + E_;
  const float* hattr  = (const float*)d_in[2];
  const int*   batch  = (const int*)d_in[3];
  const float* We     = (const float*)d_in[4];
  const float* be     = (const float*)d_in[5];
  const float* Wf1    = (const float*)d_in[6];
  const float* bf1    = (const float*)d_in[7];
  const float* Wc1    = (const float*)d_in[8];
  const float* bc1    = (const float*)d_in[9];
  const float* Wf2    = (const float*)d_in[10];
  const float* bf2    = (const float*)d_in[11];
  const float* Wc2    = (const float*)d_in[12];
  const float* bc2    = (const float*)d_in[13];
  const float* bn_f_g = (const float*)d_in[14];
  const float* bn_f_b = (const float*)d_in[15];
  const float* bn_c_g = (const float*)d_in[16];
  const float* bn_c_b = (const float*)d_in[17];
  const float* bn_o_g = (const float*)d_in[18];
  const float* bn_o_b = (const float*)d_in[19];
  const float* Wl2    = (const float*)d_in[20];
  const float* bl2    = (const float*)d_in[21];
  const float* Wo     = (const float*)d_in[22];
  const float* bo     = (const float*)d_in[23];

  float* ws = (float*)d_ws;
  size_t o = 0;
  float* h0    = ws + o; o += (size_t)N_NODES_*H_;
  float* h1    = ws + o; o += (size_t)N_NODES_*H_;
  float* tfc   = ws + o; o += (size_t)N_HEDGES_*70;    // 14.0M floats
  u32*   nFC2  = (u32*)tfc;                            // alias: tfc consumed before nFC2 written
  float* hmR   = ws + o; o += (size_t)N_HEDGES_*H_;    // 12.8M floats region
  u32*   hmean16 = (u32*)hmR;                          // 6.4M words (first half)
  u32*   heFC2   = (u32*)hmR;                          // 12.8M words; hmean16 dead before write
  float* nmean = ws + o; o += (size_t)N_NODES_*H_;
  u32*  h16a   = (u32*)(ws + o); o += (size_t)N_NODES_*32;
  u32*  h16b   = (u32*)(ws + o); o += (size_t)N_NODES_*32;
  u32*  hattr16= (u32*)(ws + o); o += (size_t)N_HEDGES_*18;
  float* hstats = ws + o; o += 256;
  float* habs   = ws + o; o += 256;
  float* nstats = ws + o; o += 128;
  float* nabs   = ws + o; o += 128;
  float* gsum   = ws + o; o += (size_t)G_*H_;
  float* hinv   = ws + o; o += N_HEDGES_;
  float* ninv   = ws + o; o += N_NODES_;
  int* hcnt     = (int*)(ws + o); o += N_HEDGES_;
  int* ndeg     = (int*)(ws + o); o += N_NODES_;
  int* gcnt     = (int*)(ws + o); o += G_;
  int* node_off = (int*)(ws + o); o += N_NODES_;
  int* hedge_off= (int*)(ws + o); o += N_HEDGES_;
  int* ncur     = (int*)(ws + o); o += N_NODES_;
  int* hcur     = (int*)(ws + o); o += N_HEDGES_;
  int* bsumA    = (int*)(ws + o); o += 1024;
  int* bsumB    = (int*)(ws + o); o += 1024;
  int* edge_n   = (int*)(ws + o); o += E_;
  int* edge_h   = (int*)(ws + o); o += E_;

  hipMemsetAsync(hcnt, 0, sizeof(int)*N_HEDGES_, stream);
  hipMemsetAsync(ndeg, 0, sizeof(int)*N_NODES_, stream);
  hipMemsetAsync(gcnt, 0, sizeof(int)*G_, stream);
  hipMemsetAsync(gsum, 0, sizeof(float)*G_*H_, stream);

  k_counts<<<(E_+255)/256, 256, 0, stream>>>(ni, hi, hcnt, ndeg);
  k_gcnt<<<(N_NODES_+255)/256, 256, 0, stream>>>(batch, gcnt);
  k_inv<<<(N_HEDGES_+255)/256, 256, 0, stream>>>(hcnt, ndeg, hinv, ninv);
  k_hattr_pack<<<(N_HEDGES_*18+255)/256, 256, 0, stream>>>(hattr, hattr16);

  k_scan1<<<(N_NODES_+255)/256, 256, 0, stream>>>(ndeg, N_NODES_, node_off, bsumA);
  k_scan2<<<1, 1024, 0, stream>>>(bsumA, (N_NODES_+255)/256);
  k_scan3<<<(N_NODES_+255)/256, 256, 0, stream>>>(node_off, bsumA, ncur, N_NODES_);
  k_scan1<<<(N_HEDGES_+255)/256, 256, 0, stream>>>(hcnt, N_HEDGES_, hedge_off, bsumB);
  k_scan2<<<1, 1024, 0, stream>>>(bsumB, (N_HEDGES_+255)/256);
  k_scan3<<<(N_HEDGES_+255)/256, 256, 0, stream>>>(hedge_off, bsumB, hcur, N_HEDGES_);
  k_fill<<<(E_+255)/256, 256, 0, stream>>>(ni, hi, ncur, hcur, edge_n, edge_h);

  k_embed<<<768, 256, 0, stream>>>(x, We, be, h0, h16a);

  float* hcur2 = h0;  u32* hc16 = h16a;
  float* hnxt  = h1;  u32* hn16 = h16b;
  for (int l = 0; l < L_; ++l){
    const float* Wf1l = Wf1 + (size_t)l*D_*HE_;
    const float* Wc1l = Wc1 + (size_t)l*D_*HE_;
    const float* Wf2l = Wf2 + (size_t)l*D_*H_;
    const float* Wc2l = Wc2 + (size_t)l*D_*H_;

    hipMemsetAsync(hstats, 0, sizeof(float)*160, stream);
    hipMemsetAsync(nstats, 0, sizeof(float)*128, stream);

    k_gather_hedge<<<(N_HEDGES_*32)/256, 256, 0, stream>>>(hc16, hedge_off, hcnt, edge_h,
                                                           hinv, hmean16);
    k_hedge_mlp1<<<1280, 256, 0, stream>>>(hmean16, hattr16, Wf1l, bf1 + l*HE_,
                                           Wc1l, bc1 + l*HE_, tfc, hstats);
    k_bn_fin_hedge<<<1, 128, 0, stream>>>(hstats, bn_f_g + l*HE_, bn_f_b + l*HE_,
                                          bn_c_g + l*HE_, bn_c_b + l*HE_, habs,
                                          1.f/(float)N_HEDGES_);
    k_hedge_feats<<<1536, 256, 0, stream>>>(tfc, habs, Wf2l, bf2 + l*H_,
                                            Wc2l, bc2 + l*H_, heFC2);
    k_node_lin<<<1024, 256, 0, stream>>>(hc16, Wf2l, Wc2l, nFC2);
    k_edge<<<2048, 256, 0, stream>>>(nFC2, heFC2, node_off, ndeg, edge_n, ninv, nmean, nstats);
    k_bn_fin_node<<<1, 64, 0, stream>>>(nstats, bn_o_g + l*H_, bn_o_b + l*H_, nabs,
                                        1.f/(float)N_NODES_);
    k_node_update<<<(N_NODES_*32+255)/256, 256, 0, stream>>>(nmean, nabs, hcur2, hnxt, hn16);
    float* t2 = hcur2; hcur2 = hnxt; hnxt = t2;
    u32* t3 = hc16; hc16 = hn16; hn16 = t3;
  }

  k_graph_agg<<<(N_NODES_*H_+255)/256, 256, 0, stream>>>(hcur2, batch, gsum);
  k_head<<<G_, 128, 0, stream>>>(gsum, gcnt, Wl2, bl2, Wo, bo, (float*)d_out);
}

// Round 8
// 1579.946 us; speedup vs baseline: 2.3660x; 1.0193x over previous
//
#include <hip/hip_runtime.h>
#include <cstddef>

#define N_NODES_  100000
#define N_HEDGES_ 200000
#define E_        1200000
#define G_        512
#define H_        64
#define HE_       35
#define D_        99      // H_+HE_
#define HOUT_     128
#define L_        3
#define NB_N_     1563    // ceil(N_NODES/64)
#define NB_H_     3125    // N_HEDGES/64

typedef unsigned int u32;
typedef unsigned long long u64;
typedef _Float16 f2_t __attribute__((ext_vector_type(2)));

__device__ __forceinline__ float sigm_(float x){
  return __builtin_amdgcn_rcpf(1.f + __expf(-x));
}
__device__ __forceinline__ float sp_(float x){
  return fmaxf(x, 0.f) + __logf(1.f + __expf(-fabsf(x)));
}
__device__ __forceinline__ float gate_(float F, float C){ return sigm_(F)*sp_(C); }

__device__ __forceinline__ u32 pk_(float a, float b){
  return __builtin_bit_cast(u32, __builtin_amdgcn_cvt_pkrtz(a, b));
}
__device__ __forceinline__ float dot2_(u32 a, u32 b, float c){
#if __has_builtin(__builtin_amdgcn_fdot2)
  return __builtin_amdgcn_fdot2(__builtin_bit_cast(f2_t, a),
                                __builtin_bit_cast(f2_t, b), c, false);
#else
  f2_t x = __builtin_bit_cast(f2_t, a), y = __builtin_bit_cast(f2_t, b);
  return c + (float)x[0]*(float)y[0] + (float)x[1]*(float)y[1];
#endif
}
__device__ __forceinline__ float lo_(u32 a){ return (float)__builtin_bit_cast(f2_t, a)[0]; }
__device__ __forceinline__ float hi_(u32 a){ return (float)__builtin_bit_cast(f2_t, a)[1]; }

// ---------------- per-call counts ----------------
__global__ void k_counts(const int* __restrict__ ni, const int* __restrict__ hi,
                         int* __restrict__ hcnt, int* __restrict__ ndeg){
  int e = blockIdx.x*256 + threadIdx.x;
  if (e >= E_) return;
  atomicAdd(&hcnt[hi[e]], 1);
  atomicAdd(&ndeg[ni[e]], 1);
}
__global__ void k_gcnt(const int* __restrict__ batch, int* __restrict__ gcnt){
  int n = blockIdx.x*256 + threadIdx.x;
  if (n < N_NODES_) atomicAdd(&gcnt[batch[n]], 1);
}
__global__ void k_inv(const int* __restrict__ hcnt, const int* __restrict__ ndeg,
                      float* __restrict__ hinv, float* __restrict__ ninv){
  int i = blockIdx.x*256 + threadIdx.x;
  if (i < N_HEDGES_) hinv[i] = 1.f/fmaxf((float)hcnt[i], 1.f);
  if (i < N_NODES_)  ninv[i] = 1.f/fmaxf((float)ndeg[i], 1.f);
}

// ---------------- CSR build: scan ----------------
__global__ void k_scan1(const int* __restrict__ cnt, int n, int* __restrict__ off,
                        int* __restrict__ bsum){
  __shared__ int tmp[256];
  int i = blockIdx.x*256 + threadIdx.x;
  int v = (i < n) ? cnt[i] : 0;
  tmp[threadIdx.x] = v;
  __syncthreads();
  for (int d = 1; d < 256; d <<= 1){
    int t = (threadIdx.x >= d) ? tmp[threadIdx.x - d] : 0;
    __syncthreads();
    tmp[threadIdx.x] += t;
    __syncthreads();
  }
  if (i < n) off[i] = tmp[threadIdx.x] - v;
  if (threadIdx.x == 255) bsum[blockIdx.x] = tmp[255];
}
__global__ void k_scan2(int* __restrict__ bsum, int nb){
  __shared__ int tmp[1024];
  int t = threadIdx.x;
  int v = (t < nb) ? bsum[t] : 0;
  tmp[t] = v;
  __syncthreads();
  for (int d = 1; d < 1024; d <<= 1){
    int x = (t >= d) ? tmp[t - d] : 0;
    __syncthreads();
    tmp[t] += x;
    __syncthreads();
  }
  if (t < nb) bsum[t] = tmp[t] - v;
}
__global__ void k_scan3(int* __restrict__ off, const int* __restrict__ bsum, int n){
  int i = blockIdx.x*256 + threadIdx.x;
  if (i < n) off[i] += bsum[blockIdx.x];
}

// ---------------- bucketed CSR fill (kills scatter write amplification) ----------------
__global__ void k_bucket_init(const int* __restrict__ node_off, const int* __restrict__ hedge_off,
                              int* __restrict__ bcurN, int* __restrict__ bcurH){
  int b = blockIdx.x*256 + threadIdx.x;
  if (b < NB_N_) bcurN[b] = node_off[b*64];
  if (b < NB_H_) bcurH[b] = hedge_off[b*64];
}
__global__ void k_binfill(const int* __restrict__ ni, const int* __restrict__ hi,
                          int* __restrict__ bcurN, int* __restrict__ bcurH,
                          u64* __restrict__ pairN, u64* __restrict__ pairH){
  int e = blockIdx.x*256 + threadIdx.x;
  if (e >= E_) return;
  int n = ni[e], he = hi[e];
  int pn = atomicAdd(&bcurN[n >> 6], 1);
  pairN[pn] = ((u64)(u32)n << 32) | (u32)he;
  int ph = atomicAdd(&bcurH[he >> 6], 1);
  pairH[ph] = ((u64)(u32)he << 32) | (u32)n;
}
// one block per bucket of 64 rows; LDS cursors; hot 3KB dest region
__global__ void k_csrfill(const int* __restrict__ off_arr, const int* __restrict__ bcur,
                          const u64* __restrict__ pair, int nitems, int* __restrict__ out){
  __shared__ int cur[64];
  int b = blockIdx.x, t = threadIdx.x;
  int nb = b*64;
  if (t < 64){
    int idx = nb + t;
    cur[t] = (idx < nitems) ? off_arr[idx] : 0;
  }
  __syncthreads();
  int base = off_arr[nb];
  int end  = bcur[b];
  for (int pos = base + t; pos < end; pos += 256){
    u64 p = pair[pos];
    int loc = (int)(p >> 32) - nb;
    int val = (int)(p & 0xffffffffu);
    int idx = atomicAdd(&cur[loc], 1);
    out[idx] = val;
  }
}

// ---------------- pack hattr to fp16 pairs [NH][18] ----------------
__global__ void k_hattr_pack(const float* __restrict__ hattr, u32* __restrict__ hattr16){
  int i = blockIdx.x*256 + threadIdx.x;
  if (i >= N_HEDGES_*18) return;
  int he = i/18, p = i - he*18;
  int k0 = 2*p, k1 = 2*p + 1;
  float w0 = (k0 < 35) ? hattr[(size_t)he*35 + k0] : 0.f;
  float w1 = (k1 < 35) ? hattr[(size_t)he*35 + k1] : 0.f;
  hattr16[i] = pk_(w0, w1);
}

// ---------------- embed: h = x @ We + be ; also packed fp16 mirror ----------------
__global__ void k_embed(const float* __restrict__ x, const float* __restrict__ We,
                        const float* __restrict__ be, float* __restrict__ h,
                        u32* __restrict__ h16){
  __shared__ __align__(16) float As[64*100];
  __shared__ __align__(16) float Ws[64*100];
  int tid = threadIdx.x;
  for (int idx = tid; idx < 64*100; idx += 256){
    int c = idx/100, k = idx - c*100;
    Ws[idx] = (k < 92) ? We[k*64 + c] : 0.f;
  }
  int rt = tid & 15, ct = tid >> 4;
  float bias[4];
  #pragma unroll
  for (int j = 0; j < 4; ++j) bias[j] = be[ct*4 + j];
  const int ntiles = (N_NODES_ + 63)/64;
  for (int tile = blockIdx.x; tile < ntiles; tile += gridDim.x){
    int rbase = tile*64;
    __syncthreads();
    for (int idx = tid; idx < 64*100; idx += 256){
      int r = idx/100, k = idx - r*100;
      int rg = rbase + r;
      As[idx] = (rg < N_NODES_ && k < 92) ? x[(size_t)rg*92 + k] : 0.f;
    }
    __syncthreads();
    float acc[4][4] = {};
    for (int kc = 0; kc < 25; ++kc){
      float4 av[4], wv[4];
      #pragma unroll
      for (int i = 0; i < 4; ++i) av[i] = *(const float4*)&As[(rt + 16*i)*100 + kc*4];
      #pragma unroll
      for (int j = 0; j < 4; ++j) wv[j] = *(const float4*)&Ws[(ct*4 + j)*100 + kc*4];
      #pragma unroll
      for (int i = 0; i < 4; ++i)
        #pragma unroll
        for (int j = 0; j < 4; ++j)
          acc[i][j] += av[i].x*wv[j].x + av[i].y*wv[j].y + av[i].z*wv[j].z + av[i].w*wv[j].w;
    }
    #pragma unroll
    for (int i = 0; i < 4; ++i){
      int r = rbase + rt + 16*i;
      if (r < N_NODES_){
        float4 st;
        st.x = acc[i][0] + bias[0]; st.y = acc[i][1] + bias[1];
        st.z = acc[i][2] + bias[2]; st.w = acc[i][3] + bias[3];
        *(float4*)&h[(size_t)r*64 + ct*4] = st;
        h16[(size_t)r*32 + ct*2]     = pk_(st.x, st.y);
        h16[(size_t)r*32 + ct*2 + 1] = pk_(st.z, st.w);
      }
    }
  }
}

// ---------------- hedge gather (fp16, uint2): hmean16[he] = mean of h16 rows ----------------
__global__ void __launch_bounds__(256) k_gather_hedge(
    const u32* __restrict__ h16, const int* __restrict__ hedge_off,
    const int* __restrict__ hcnt, const int* __restrict__ edge_h,
    const float* __restrict__ hinv, u32* __restrict__ hmean16){
  int w = (blockIdx.x*256 + threadIdx.x) >> 4;
  int p = threadIdx.x & 15;
  if (w >= N_HEDGES_) return;
  int off = hedge_off[w], deg = hcnt[w];
  float a0 = 0.f, a1 = 0.f, a2 = 0.f, a3 = 0.f;
  int i = 0;
  for (; i + 1 < deg; i += 2){
    int n0 = edge_h[off+i], n1 = edge_h[off+i+1];
    uint2 u0 = *(const uint2*)&h16[(size_t)n0*32 + 2*p];
    uint2 u1 = *(const uint2*)&h16[(size_t)n1*32 + 2*p];
    a0 += lo_(u0.x) + lo_(u1.x); a1 += hi_(u0.x) + hi_(u1.x);
    a2 += lo_(u0.y) + lo_(u1.y); a3 += hi_(u0.y) + hi_(u1.y);
  }
  if (i < deg){
    uint2 u = *(const uint2*)&h16[(size_t)edge_h[off+i]*32 + 2*p];
    a0 += lo_(u.x); a1 += hi_(u.x); a2 += lo_(u.y); a3 += hi_(u.y);
  }
  float inv = hinv[w];
  uint2 st; st.x = pk_(a0*inv, a1*inv); st.y = pk_(a2*inv, a3*inv);
  *(uint2*)&hmean16[(size_t)w*32 + 2*p] = st;
}

// ---------------- hedge MLP pre-BN (dot2): tfc = [msg@Wf1|msg@Wc1]+b, col stats ----------
__global__ void k_hedge_mlp1(const u32* __restrict__ hmean16, const u32* __restrict__ hattr16,
                             const float* __restrict__ Wf1, const float* __restrict__ bf1,
                             const float* __restrict__ Wc1, const float* __restrict__ bc1,
                             float* __restrict__ tfc, float* __restrict__ hstats){
  __shared__ __align__(16) u32 As16[64*52];
  __shared__ __align__(16) u32 Ws16[80*52];
  __shared__ float sstat[160];
  int tid = threadIdx.x;
  for (int idx = tid; idx < 80*52; idx += 256){
    int c = idx/52, kk = idx - c*52;
    int k0 = 2*kk, k1 = 2*kk + 1;
    float w0 = 0.f, w1 = 0.f;
    if (c < 70){
      if (k0 < 99) w0 = (c < 35) ? Wf1[k0*35 + c] : Wc1[k0*35 + (c-35)];
      if (k1 < 99) w1 = (c < 35) ? Wf1[k1*35 + c] : Wc1[k1*35 + (c-35)];
    }
    Ws16[idx] = pk_(w0, w1);
  }
  for (int idx = tid; idx < 160; idx += 256) sstat[idx] = 0.f;
  int rt = tid & 15, ct = tid >> 4;
  float bias[5];
  #pragma unroll
  for (int j = 0; j < 5; ++j){
    int c = ct*5 + j;
    bias[j] = (c < 35) ? bf1[c] : (c < 70 ? bc1[c - 35] : 0.f);
  }
  for (int tile = blockIdx.x; tile < N_HEDGES_/64; tile += gridDim.x){
    int rbase = tile*64;
    __syncthreads();
    for (int idx = tid; idx < 64*52; idx += 256){
      int r = idx/52, kk = idx - r*52;
      int rg = rbase + r;
      u32 v = 0;
      if (kk < 32)      v = hmean16[(size_t)rg*32 + kk];
      else if (kk < 50) v = hattr16[(size_t)rg*18 + (kk - 32)];
      As16[idx] = v;
    }
    __syncthreads();
    float acc[4][5] = {};
    for (int kc = 0; kc < 13; ++kc){
      uint4 av[4], wv[5];
      #pragma unroll
      for (int i = 0; i < 4; ++i) av[i] = *(const uint4*)&As16[(rt + 16*i)*52 + kc*4];
      #pragma unroll
      for (int j = 0; j < 5; ++j) wv[j] = *(const uint4*)&Ws16[(ct*5 + j)*52 + kc*4];
      #pragma unroll
      for (int i = 0; i < 4; ++i)
        #pragma unroll
        for (int j = 0; j < 5; ++j){
          float a = acc[i][j];
          a = dot2_(av[i].x, wv[j].x, a);
          a = dot2_(av[i].y, wv[j].y, a);
          a = dot2_(av[i].z, wv[j].z, a);
          a = dot2_(av[i].w, wv[j].w, a);
          acc[i][j] = a;
        }
    }
    #pragma unroll
    for (int j = 0; j < 5; ++j){
      int c = ct*5 + j;
      if (c < 70){
        float s = 0.f, q = 0.f;
        #pragma unroll
        for (int i = 0; i < 4; ++i){
          float v = acc[i][j] + bias[j];
          int r = rbase + rt + 16*i;
          tfc[(size_t)r*70 + c] = v;
          s += v; q += v*v;
        }
        atomicAdd(&sstat[c], s);
        atomicAdd(&sstat[80 + c], q);
      }
    }
  }
  __syncthreads();
  for (int idx = tid; idx < 160; idx += 256) atomicAdd(&hstats[idx], sstat[idx]);
}

// ---------------- BN finalize (hedge) ----------------
__global__ void k_bn_fin_hedge(const float* __restrict__ stats,
                               const float* __restrict__ gf, const float* __restrict__ btf,
                               const float* __restrict__ gc, const float* __restrict__ btc,
                               float* __restrict__ ab, float invN){
  int j = threadIdx.x;
  if (j >= 70) return;
  float m = stats[j]*invN;
  float var = stats[80+j]*invN - m*m;
  float gg = (j < 35) ? gf[j] : gc[j-35];
  float bb = (j < 35) ? btf[j] : btc[j-35];
  float a = gg*rsqrtf(var + 1e-5f);
  ab[j] = a; ab[70+j] = bb - m*a;
}

// ---------------- hedge feats + project (dot2): heFC2 packed fp16 ------------
__global__ void k_hedge_feats(const float* __restrict__ tfc, const float* __restrict__ ab,
                              const float* __restrict__ Wf2, const float* __restrict__ bf2,
                              const float* __restrict__ Wc2, const float* __restrict__ bc2,
                              u32* __restrict__ heFC2){
  __shared__ __align__(16) u32 As16[64*20];
  __shared__ __align__(16) u32 Ws16[128*20];
  int tid = threadIdx.x;
  for (int idx = tid; idx < 128*20; idx += 256){
    int c = idx/20, kk = idx - c*20;
    int k0 = 2*kk, k1 = 2*kk + 1;
    float w0 = 0.f, w1 = 0.f;
    if (k0 < 35) w0 = (c < 64) ? Wf2[(64+k0)*64 + c] : Wc2[(64+k0)*64 + (c-64)];
    if (k1 < 35) w1 = (c < 64) ? Wf2[(64+k1)*64 + c] : Wc2[(64+k1)*64 + (c-64)];
    Ws16[idx] = pk_(w0, w1);
  }
  int rt = tid & 15, ct = tid >> 4;
  float biasF[4], biasC[4];
  #pragma unroll
  for (int j = 0; j < 4; ++j){ biasF[j] = bf2[ct*4 + j]; biasC[j] = bc2[ct*4 + j]; }
  for (int tile = blockIdx.x; tile < N_HEDGES_/64; tile += gridDim.x){
    int rbase = tile*64;
    __syncthreads();
    for (int idx = tid; idx < 64*20; idx += 256){
      int r = idx/20, kk = idx - r*20;
      int rg = rbase + r;
      int k0 = 2*kk, k1 = 2*kk + 1;
      float a0 = 0.f, a1 = 0.f;
      if (k0 < 35){
        float zf = ab[k0]    * tfc[(size_t)rg*70 + k0]      + ab[70 + k0];
        float zc = ab[35+k0] * tfc[(size_t)rg*70 + 35 + k0] + ab[105 + k0];
        a0 = gate_(zf, zc);
      }
      if (k1 < 35){
        float zf = ab[k1]    * tfc[(size_t)rg*70 + k1]      + ab[70 + k1];
        float zc = ab[35+k1] * tfc[(size_t)rg*70 + 35 + k1] + ab[105 + k1];
        a1 = gate_(zf, zc);
      }
      As16[idx] = pk_(a0, a1);
    }
    __syncthreads();
    float accF[4][4] = {}, accC[4][4] = {};
    for (int kc = 0; kc < 5; ++kc){
      uint4 av[4], wF[4], wC[4];
      #pragma unroll
      for (int i = 0; i < 4; ++i) av[i] = *(const uint4*)&As16[(rt + 16*i)*20 + kc*4];
      #pragma unroll
      for (int j = 0; j < 4; ++j){
        wF[j] = *(const uint4*)&Ws16[(ct*4 + j)*20 + kc*4];
        wC[j] = *(const uint4*)&Ws16[(64 + ct*4 + j)*20 + kc*4];
      }
      #pragma unroll
      for (int i = 0; i < 4; ++i)
        #pragma unroll
        for (int j = 0; j < 4; ++j){
          float f = accF[i][j], c = accC[i][j];
          f = dot2_(av[i].x, wF[j].x, f); c = dot2_(av[i].x, wC[j].x, c);
          f = dot2_(av[i].y, wF[j].y, f); c = dot2_(av[i].y, wC[j].y, c);
          f = dot2_(av[i].z, wF[j].z, f); c = dot2_(av[i].z, wC[j].z, c);
          f = dot2_(av[i].w, wF[j].w, f); c = dot2_(av[i].w, wC[j].w, c);
          accF[i][j] = f; accC[i][j] = c;
        }
    }
    #pragma unroll
    for (int i = 0; i < 4; ++i){
      int r = rbase + rt + 16*i;
      #pragma unroll
      for (int j = 0; j < 4; ++j){
        heFC2[(size_t)r*64 + ct*4 + j] = pk_(accF[i][j] + biasF[j], accC[i][j] + biasC[j]);
      }
    }
  }
}

// ---------------- node projections (dot2): nFC2 packed fp16 ----------------
__global__ void k_node_lin(const u32* __restrict__ h16,
                           const float* __restrict__ Wf2, const float* __restrict__ Wc2,
                           u32* __restrict__ nFC2){
  __shared__ __align__(16) u32 As16[64*36];
  __shared__ __align__(16) u32 Ws16[128*36];
  int tid = threadIdx.x;
  for (int idx = tid; idx < 128*36; idx += 256){
    int c = idx/36, kk = idx - c*36;
    int k0 = 2*kk, k1 = 2*kk + 1;
    float w0 = 0.f, w1 = 0.f;
    if (k0 < 64) w0 = (c < 64) ? Wf2[k0*64 + c] : Wc2[k0*64 + (c-64)];
    if (k1 < 64) w1 = (c < 64) ? Wf2[k1*64 + c] : Wc2[k1*64 + (c-64)];
    Ws16[idx] = pk_(w0, w1);
  }
  int rt = tid & 15, ct = tid >> 4;
  const int ntiles = (N_NODES_ + 63)/64;
  for (int tile = blockIdx.x; tile < ntiles; tile += gridDim.x){
    int rbase = tile*64;
    __syncthreads();
    for (int idx = tid; idx < 64*36; idx += 256){
      int r = idx/36, kk = idx - r*36;
      int rg = rbase + r;
      As16[idx] = (rg < N_NODES_ && kk < 32) ? h16[(size_t)rg*32 + kk] : 0u;
    }
    __syncthreads();
    float accF[4][4] = {}, accC[4][4] = {};
    for (int kc = 0; kc < 8; ++kc){
      uint4 av[4], wF[4], wC[4];
      #pragma unroll
      for (int i = 0; i < 4; ++i) av[i] = *(const uint4*)&As16[(rt + 16*i)*36 + kc*4];
      #pragma unroll
      for (int j = 0; j < 4; ++j){
        wF[j] = *(const uint4*)&Ws16[(ct*4 + j)*36 + kc*4];
        wC[j] = *(const uint4*)&Ws16[(64 + ct*4 + j)*36 + kc*4];
      }
      #pragma unroll
      for (int i = 0; i < 4; ++i)
        #pragma unroll
        for (int j = 0; j < 4; ++j){
          float f = accF[i][j], c = accC[i][j];
          f = dot2_(av[i].x, wF[j].x, f); c = dot2_(av[i].x, wC[j].x, c);
          f = dot2_(av[i].y, wF[j].y, f); c = dot2_(av[i].y, wC[j].y, c);
          f = dot2_(av[i].z, wF[j].z, f); c = dot2_(av[i].z, wC[j].z, c);
          f = dot2_(av[i].w, wF[j].w, f); c = dot2_(av[i].w, wC[j].w, c);
          accF[i][j] = f; accC[i][j] = c;
        }
    }
    #pragma unroll
    for (int i = 0; i < 4; ++i){
      int r = rbase + rt + 16*i;
      if (r < N_NODES_){
        #pragma unroll
        for (int j = 0; j < 4; ++j){
          nFC2[(size_t)r*64 + ct*4 + j] = pk_(accF[i][j], accC[i][j]);
        }
      }
    }
  }
}

// ---------------- fused edge: node-CSR gather + gated act + mean + stats ------
__global__ void k_edge(const u32* __restrict__ nFC2, const u32* __restrict__ heFC2,
                       const int* __restrict__ node_off, const int* __restrict__ ndeg,
                       const int* __restrict__ edge_n, const float* __restrict__ ninv,
                       float* __restrict__ nmean, float* __restrict__ nstats){
  int lane = threadIdx.x & 63, wave = threadIdx.x >> 6;
  float s = 0.f, q = 0.f;
  for (int base = blockIdx.x*4; base < N_NODES_; base += gridDim.x*4){
    int n = base + wave;
    if (n < N_NODES_){
      int off = __builtin_amdgcn_readfirstlane(node_off[n]);
      int deg = __builtin_amdgcn_readfirstlane(ndeg[n]);
      u32 p0 = nFC2[(size_t)n*64 + lane];
      float f0 = lo_(p0), c0 = hi_(p0);
      float acc = 0.f;
      int i = 0;
      for (; i + 3 < deg; i += 4){
        int e0 = edge_n[off+i], e1 = edge_n[off+i+1], e2 = edge_n[off+i+2], e3 = edge_n[off+i+3];
        u32 a0 = heFC2[(size_t)e0*64 + lane];
        u32 a1 = heFC2[(size_t)e1*64 + lane];
        u32 a2 = heFC2[(size_t)e2*64 + lane];
        u32 a3 = heFC2[(size_t)e3*64 + lane];
        acc += gate_(f0 + lo_(a0), c0 + hi_(a0))
             + gate_(f0 + lo_(a1), c0 + hi_(a1))
             + gate_(f0 + lo_(a2), c0 + hi_(a2))
             + gate_(f0 + lo_(a3), c0 + hi_(a3));
      }
      for (; i < deg; ++i){
        u32 a = heFC2[(size_t)edge_n[off+i]*64 + lane];
        acc += gate_(f0 + lo_(a), c0 + hi_(a));
      }
      float m = acc * ninv[n];
      nmean[(size_t)n*64 + lane] = m;
      s += m; q += m*m;
    }
  }
  __shared__ float p1[256], p2[256];
  p1[threadIdx.x] = s; p2[threadIdx.x] = q;
  __syncthreads();
  if (wave == 0){
    float a = p1[lane] + p1[64+lane] + p1[128+lane] + p1[192+lane];
    float b = p2[lane] + p2[64+lane] + p2[128+lane] + p2[192+lane];
    atomicAdd(&nstats[lane], a);
    atomicAdd(&nstats[64+lane], b);
  }
}

__global__ void k_bn_fin_node(const float* __restrict__ stats, const float* __restrict__ g,
                              const float* __restrict__ bt, float* __restrict__ ab, float invN){
  int j = threadIdx.x;
  if (j >= 64) return;
  float m = stats[j]*invN;
  float var = stats[64+j]*invN - m*m;
  float a = g[j]*rsqrtf(var + 1e-5f);
  ab[j] = a; ab[64+j] = bt[j] - m*a;
}

// ---------------- node update: h' = softplus(BN(mean) + h), + fp16 mirror ----------------
__global__ void k_node_update(const float* __restrict__ nmean, const float* __restrict__ ab,
                              const float* __restrict__ h, float* __restrict__ hout,
                              u32* __restrict__ h16out){
  int t = blockIdx.x*256 + threadIdx.x;
  if (t >= N_NODES_*32) return;
  int p = t & 31;
  int f0 = 2*p, f1 = 2*p + 1;
  float2 nm = ((const float2*)nmean)[t];
  float2 hh = ((const float2*)h)[t];
  float r0 = sp_(ab[f0]*nm.x + ab[64+f0] + hh.x);
  float r1 = sp_(ab[f1]*nm.y + ab[64+f1] + hh.y);
  float2 st; st.x = r0; st.y = r1;
  ((float2*)hout)[t] = st;
  h16out[t] = pk_(r0, r1);
}

// ---------------- graph mean + head ----------------
__global__ void k_graph_agg(const float* __restrict__ h, const int* __restrict__ batch,
                            float* __restrict__ gsum){
  int t = blockIdx.x*256 + threadIdx.x;
  int n = t >> 6; if (n >= N_NODES_) return;
  int f = t & 63;
  atomicAdd(&gsum[(size_t)batch[n]*64+f], h[t]);
}

__global__ void k_head(const float* __restrict__ gsum, const int* __restrict__ gcnt,
                       const float* __restrict__ Wl2, const float* __restrict__ bl2,
                       const float* __restrict__ Wo, const float* __restrict__ bo,
                       float* __restrict__ out){
  __shared__ float gm[64];
  __shared__ float red[128];
  int g = blockIdx.x, j = threadIdx.x;
  if (j < 64) gm[j] = gsum[(size_t)g*64+j] / fmaxf((float)gcnt[g], 1.f);
  __syncthreads();
  float u = bl2[j];
  for (int f = 0; f < 64; ++f) u += gm[f]*Wl2[f*128+j];
  red[j] = sp_(u)*Wo[j];
  __syncthreads();
  for (int s = 64; s > 0; s >>= 1){
    if (j < s) red[j] += red[j+s];
    __syncthreads();
  }
  if (j == 0) out[g] = red[0] + bo[0];
}

extern "C" void kernel_launch(void* const* d_in, const int* in_sizes, int n_in,
                              void* d_out, int out_size, void* d_ws, size_t ws_size,
                              hipStream_t stream){
  (void)in_sizes; (void)n_in; (void)out_size; (void)ws_size;
  const float* x      = (const float*)d_in[0];
  const int*   ni     = (const int*)d_in[1];
  const int*   hi     = ni + E_;
  const float* hattr  = (const float*)d_in[2];
  const int*   batch  = (const int*)d_in[3];
  const float* We     = (const float*)d_in[4];
  const float* be     = (const float*)d_in[5];
  const float* Wf1    = (const float*)d_in[6];
  const float* bf1    = (const float*)d_in[7];
  const float* Wc1    = (const float*)d_in[8];
  const float* bc1    = (const float*)d_in[9];
  const float* Wf2    = (const float*)d_in[10];
  const float* bf2    = (const float*)d_in[11];
  const float* Wc2    = (const float*)d_in[12];
  const float* bc2    = (const float*)d_in[13];
  const float* bn_f_g = (const float*)d_in[14];
  const float* bn_f_b = (const float*)d_in[15];
  const float* bn_c_g = (const float*)d_in[16];
  const float* bn_c_b = (const float*)d_in[17];
  const float* bn_o_g = (const float*)d_in[18];
  const float* bn_o_b = (const float*)d_in[19];
  const float* Wl2    = (const float*)d_in[20];
  const float* bl2    = (const float*)d_in[21];
  const float* Wo     = (const float*)d_in[22];
  const float* bo     = (const float*)d_in[23];

  float* ws = (float*)d_ws;
  size_t o = 0;
  float* h0    = ws + o; o += (size_t)N_NODES_*H_;
  float* h1    = ws + o; o += (size_t)N_NODES_*H_;
  float* tfc   = ws + o; o += (size_t)N_HEDGES_*70;    // 14.0M floats
  u32*   nFC2  = (u32*)tfc;                            // alias: layer-time
  u64*   pairN = (u64*)tfc;                            // alias: CSR-build-time only
  u64*   pairH = ((u64*)tfc) + E_;
  float* hmR   = ws + o; o += (size_t)N_HEDGES_*H_;    // 12.8M floats region
  u32*   hmean16 = (u32*)hmR;
  u32*   heFC2   = (u32*)hmR;                          // hmean16 dead before heFC2 written
  float* nmean = ws + o; o += (size_t)N_NODES_*H_;
  u32*  h16a   = (u32*)(ws + o); o += (size_t)N_NODES_*32;
  u32*  h16b   = (u32*)(ws + o); o += (size_t)N_NODES_*32;
  u32*  hattr16= (u32*)(ws + o); o += (size_t)N_HEDGES_*18;
  float* hstats = ws + o; o += 256;
  float* habs   = ws + o; o += 256;
  float* nstats = ws + o; o += 128;
  float* nabs   = ws + o; o += 128;
  float* gsum   = ws + o; o += (size_t)G_*H_;
  float* hinv   = ws + o; o += N_HEDGES_;
  float* ninv   = ws + o; o += N_NODES_;
  int* hcnt     = (int*)(ws + o); o += N_HEDGES_;
  int* ndeg     = (int*)(ws + o); o += N_NODES_;
  int* gcnt     = (int*)(ws + o); o += G_;
  int* node_off = (int*)(ws + o); o += N_NODES_;
  int* hedge_off= (int*)(ws + o); o += N_HEDGES_;
  int* bcurN    = (int*)(ws + o); o += NB_N_;
  int* bcurH    = (int*)(ws + o); o += NB_H_;
  int* bsumA    = (int*)(ws + o); o += 1024;
  int* bsumB    = (int*)(ws + o); o += 1024;
  int* edge_n   = (int*)(ws + o); o += E_;
  int* edge_h   = (int*)(ws + o); o += E_;

  hipMemsetAsync(hcnt, 0, sizeof(int)*N_HEDGES_, stream);
  hipMemsetAsync(ndeg, 0, sizeof(int)*N_NODES_, stream);
  hipMemsetAsync(gcnt, 0, sizeof(int)*G_, stream);
  hipMemsetAsync(gsum, 0, sizeof(float)*G_*H_, stream);

  k_counts<<<(E_+255)/256, 256, 0, stream>>>(ni, hi, hcnt, ndeg);
  k_gcnt<<<(N_NODES_+255)/256, 256, 0, stream>>>(batch, gcnt);
  k_inv<<<(N_HEDGES_+255)/256, 256, 0, stream>>>(hcnt, ndeg, hinv, ninv);
  k_hattr_pack<<<(N_HEDGES_*18+255)/256, 256, 0, stream>>>(hattr, hattr16);

  // CSR offsets
  k_scan1<<<(N_NODES_+255)/256, 256, 0, stream>>>(ndeg, N_NODES_, node_off, bsumA);
  k_scan2<<<1, 1024, 0, stream>>>(bsumA, (N_NODES_+255)/256);
  k_scan3<<<(N_NODES_+255)/256, 256, 0, stream>>>(node_off, bsumA, N_NODES_);
  k_scan1<<<(N_HEDGES_+255)/256, 256, 0, stream>>>(hcnt, N_HEDGES_, hedge_off, bsumB);
  k_scan2<<<1, 1024, 0, stream>>>(bsumB, (N_HEDGES_+255)/256);
  k_scan3<<<(N_HEDGES_+255)/256, 256, 0, stream>>>(hedge_off, bsumB, N_HEDGES_);

  // bucketed CSR fill (write-coalesced)
  k_bucket_init<<<(NB_H_+255)/256, 256, 0, stream>>>(node_off, hedge_off, bcurN, bcurH);
  k_binfill<<<(E_+255)/256, 256, 0, stream>>>(ni, hi, bcurN, bcurH, pairN, pairH);
  k_csrfill<<<NB_N_, 256, 0, stream>>>(node_off, bcurN, pairN, N_NODES_, edge_n);
  k_csrfill<<<NB_H_, 256, 0, stream>>>(hedge_off, bcurH, pairH, N_HEDGES_, edge_h);

  k_embed<<<768, 256, 0, stream>>>(x, We, be, h0, h16a);

  float* hcur2 = h0;  u32* hc16 = h16a;
  float* hnxt  = h1;  u32* hn16 = h16b;
  for (int l = 0; l < L_; ++l){
    const float* Wf1l = Wf1 + (size_t)l*D_*HE_;
    const float* Wc1l = Wc1 + (size_t)l*D_*HE_;
    const float* Wf2l = Wf2 + (size_t)l*D_*H_;
    const float* Wc2l = Wc2 + (size_t)l*D_*H_;

    hipMemsetAsync(hstats, 0, sizeof(float)*160, stream);
    hipMemsetAsync(nstats, 0, sizeof(float)*128, stream);

    k_gather_hedge<<<(N_HEDGES_*16)/256, 256, 0, stream>>>(hc16, hedge_off, hcnt, edge_h,
                                                           hinv, hmean16);
    k_hedge_mlp1<<<1280, 256, 0, stream>>>(hmean16, hattr16, Wf1l, bf1 + l*HE_,
                                           Wc1l, bc1 + l*HE_, tfc, hstats);
    k_bn_fin_hedge<<<1, 128, 0, stream>>>(hstats, bn_f_g + l*HE_, bn_f_b + l*HE_,
                                          bn_c_g + l*HE_, bn_c_b + l*HE_, habs,
                                          1.f/(float)N_HEDGES_);
    k_hedge_feats<<<1536, 256, 0, stream>>>(tfc, habs, Wf2l, bf2 + l*H_,
                                            Wc2l, bc2 + l*H_, heFC2);
    k_node_lin<<<1024, 256, 0, stream>>>(hc16, Wf2l, Wc2l, nFC2);
    k_edge<<<2048, 256, 0, stream>>>(nFC2, heFC2, node_off, ndeg, edge_n, ninv, nmean, nstats);
    k_bn_fin_node<<<1, 64, 0, stream>>>(nstats, bn_o_g + l*H_, bn_o_b + l*H_, nabs,
                                        1.f/(float)N_NODES_);
    k_node_update<<<(N_NODES_*32+255)/256, 256, 0, stream>>>(nmean, nabs, hcur2, hnxt, hn16);
    float* t2 = hcur2; hcur2 = hnxt; hnxt = t2;
    u32* t3 = hc16; hc16 = hn16; hn16 = t3;
  }

  k_graph_agg<<<(N_NODES_*H_+255)/256, 256, 0, stream>>>(hcur2, batch, gsum);
  k_head<<<G_, 128, 0, stream>>>(gsum, gcnt, Wl2, bl2, Wo, bo, (float*)d_out);
}